// Round 1
// baseline (784.780 us; speedup 1.0000x reference)
//
#include <hip/hip_runtime.h>

typedef __attribute__((ext_vector_type(8))) short bf16x8;
typedef __attribute__((ext_vector_type(8))) unsigned short ushort8;
typedef __attribute__((ext_vector_type(4))) float f32x4;

#define BM 128
#define BN 128
#define BK 64

// ---------- helpers ----------
__device__ __forceinline__ unsigned short f2bf(float f) {
  union { float f; unsigned u; } c; c.f = f;
  return (unsigned short)((c.u + 0x7fffu + ((c.u >> 16) & 1u)) >> 16);  // RNE
}
__device__ __forceinline__ float bf2f(unsigned short u) {
  union { unsigned u; float f; } c; c.u = ((unsigned)u) << 16;
  return c.f;
}
__device__ __forceinline__ void gload16(const void* g, void* lds) {
  __builtin_amdgcn_global_load_lds(
      (const __attribute__((address_space(1))) unsigned int*)g,
      (__attribute__((address_space(3))) unsigned int*)lds, 16, 0, 0);
}

// ---------- prep: transpose+convert Wk, Wg (fp32 [H,A] -> bf16 [A,H]) ----------
__global__ __launch_bounds__(256) void transpose_kernel(
    const float* __restrict__ Wk, const float* __restrict__ Wg,
    unsigned short* __restrict__ WkT, unsigned short* __restrict__ WgT) {
  __shared__ float tile[64][65];
  int bid = blockIdx.x;              // 512 = 2 mats * 16*16 tiles
  int mat = bid >> 8;
  int tid = bid & 255;
  int tr = tid >> 4, tc = tid & 15;
  const float* src = mat ? Wg : Wk;
  unsigned short* dst = mat ? WgT : WkT;
  int r0 = tr * 64, c0 = tc * 64;    // src: rows h (r0), cols a (c0)
  int t = threadIdx.x;
  int lr = t >> 6, lc = t & 63;
#pragma unroll
  for (int i = 0; i < 16; ++i) {
    int r = i * 4 + lr;
    tile[r][lc] = src[(size_t)(r0 + r) * 1024 + c0 + lc];
  }
  __syncthreads();
#pragma unroll
  for (int i = 0; i < 16; ++i) {
    int r = i * 4 + lr;  // dst row = a = c0+r, dst col = h = r0+lc
    dst[(size_t)(c0 + r) * 1024 + r0 + lc] = f2bf(tile[lc][r]);
  }
}

// ---------- prep: qb[b,a] = q[b]·Wq[:,a] + bq[a] + bk[a] ----------
__global__ __launch_bounds__(256) void query_kernel(
    const float* __restrict__ q, const float* __restrict__ Wq,
    const float* __restrict__ bq, const float* __restrict__ bk,
    float* __restrict__ qb) {
  __shared__ float qs[1024];
  int b = blockIdx.x, a0 = blockIdx.y * 256, t = threadIdx.x;
#pragma unroll
  for (int i = 0; i < 4; ++i) qs[i * 256 + t] = q[(size_t)b * 1024 + i * 256 + t];
  __syncthreads();
  int a = a0 + t;
  float acc = bq[a] + bk[a];
#pragma unroll 4
  for (int h = 0; h < 1024; ++h) acc += qs[h] * Wq[(size_t)h * 1024 + a];
  qb[(size_t)b * 1024 + a] = acc;
}

// ---------- shared GEMM core: C[128x128] over K=1024, bf16 MFMA ----------
// A (global): row-major [M,1024]; fp32 (A_IS_F32=1, reg-stage+convert) or bf16 (global_load_lds)
// B (global): WT bf16 [N,1024] (transposed weights, K contiguous)
// LDS layout: [row][8 slots of 8 bf16], slot XOR-swizzled by (row&7).
template <int A_IS_F32>
__device__ __forceinline__ void gemm_core(const void* Aptr, const unsigned short* Bptr,
                                          int m0, int n0, int t,
                                          unsigned short* As, unsigned short* Bs,
                                          f32x4 (&acc)[4][4]) {
  const int lane = t & 63;
  const int wave = t >> 6;
  const int wr = wave >> 1, wc = wave & 1;
  for (int kt = 0; kt < 16; ++kt) {
    const int k0 = kt * 64;
    __syncthreads();
    // stage B: 1024 chunks of 16B via global_load_lds (linear dest, inverse-swz source)
#pragma unroll
    for (int r = 0; r < 4; ++r) {
      int c0 = r * 256 + wave * 64;
      int c = c0 + lane;
      int n = c >> 3, s = c & 7;
      int sg = s ^ (n & 7);
      gload16(Bptr + (size_t)(n0 + n) * 1024 + k0 + sg * 8, (char*)Bs + c0 * 16);
    }
    if (A_IS_F32) {
      // reg-stage: load 8 fp32, convert, swizzled ds_write
#pragma unroll
      for (int r = 0; r < 4; ++r) {
        int c = r * 256 + t;
        int m = c >> 3, s = c & 7;
        const float* gp = (const float*)Aptr + (size_t)(m0 + m) * 1024 + k0 + s * 8;
        f32x4 v0 = *(const f32x4*)gp;
        f32x4 v1 = *(const f32x4*)(gp + 4);
        ushort8 o;
        o[0] = f2bf(v0[0]); o[1] = f2bf(v0[1]); o[2] = f2bf(v0[2]); o[3] = f2bf(v0[3]);
        o[4] = f2bf(v1[0]); o[5] = f2bf(v1[1]); o[6] = f2bf(v1[2]); o[7] = f2bf(v1[3]);
        *(ushort8*)((char*)As + m * 128 + ((s ^ (m & 7)) * 16)) = o;
      }
    } else {
#pragma unroll
      for (int r = 0; r < 4; ++r) {
        int c0 = r * 256 + wave * 64;
        int c = c0 + lane;
        int m = c >> 3, s = c & 7;
        int sg = s ^ (m & 7);
        gload16((const unsigned short*)Aptr + (size_t)(m0 + m) * 1024 + k0 + sg * 8,
                (char*)As + c0 * 16);
      }
    }
    __syncthreads();
#pragma unroll
    for (int kk = 0; kk < 2; ++kk) {
      bf16x8 av[4], bv[4];
#pragma unroll
      for (int mi = 0; mi < 4; ++mi) {
        int ml = wr * 64 + mi * 16 + (lane & 15);
        int s = kk * 4 + (lane >> 4);
        av[mi] = *(const bf16x8*)((const char*)As + ml * 128 + ((s ^ (ml & 7)) * 16));
      }
#pragma unroll
      for (int ni = 0; ni < 4; ++ni) {
        int nl = wc * 64 + ni * 16 + (lane & 15);
        int s = kk * 4 + (lane >> 4);
        bv[ni] = *(const bf16x8*)((const char*)Bs + nl * 128 + ((s ^ (nl & 7)) * 16));
      }
#pragma unroll
      for (int mi = 0; mi < 4; ++mi)
#pragma unroll
        for (int ni = 0; ni < 4; ++ni)
          acc[mi][ni] =
              __builtin_amdgcn_mfma_f32_16x16x32_bf16(av[mi], bv[ni], acc[mi][ni], 0, 0, 0);
    }
  }
}

__device__ __forceinline__ void tile_coords(int bid, int& m0, int& n0, int& nt) {
  // XCD-aware bijective swizzle (4096 blocks, 8 XCDs); n-tile fastest within an XCD
  int lin = (bid & 7) * 512 + (bid >> 3);
  int mt = lin >> 3;
  nt = lin & 7;
  m0 = mt * BM;
  n0 = nt * BN;
}

// ---------- GEMM1: align = tanh(seq@Wk + bk + query) -> bf16 ----------
__global__ __launch_bounds__(256) void gemm1_kernel(
    const float* __restrict__ seq, const unsigned short* __restrict__ WkT,
    const float* __restrict__ qb, unsigned short* __restrict__ alignb) {
  __shared__ unsigned short As[BM * BK];
  __shared__ unsigned short Bs[BN * BK];
  int m0, n0, nt;
  tile_coords(blockIdx.x, m0, n0, nt);
  int t = threadIdx.x;
  f32x4 acc[4][4] = {};
  gemm_core<1>(seq, WkT, m0, n0, t, As, Bs, acc);
  int lane = t & 63, wave = t >> 6, wr = wave >> 1, wc = wave & 1;
  const float* qrow = qb + (size_t)(m0 >> 11) * 1024;  // 128-row tile stays in one batch
#pragma unroll
  for (int mi = 0; mi < 4; ++mi) {
    int row0 = m0 + wr * 64 + mi * 16 + ((lane >> 4) * 4);
#pragma unroll
    for (int ni = 0; ni < 4; ++ni) {
      int col = n0 + wc * 64 + ni * 16 + (lane & 15);
      float qv = qrow[col];
#pragma unroll
      for (int j = 0; j < 4; ++j) {
        float v = tanhf(acc[mi][ni][j] + qv);
        alignb[(size_t)(row0 + j) * 1024 + col] = f2bf(v);
      }
    }
  }
}

// ---------- GEMM2: scores_part[nt,row] = sum_col align*sigmoid(align@Wg+bg)*Ws ----------
__global__ __launch_bounds__(256) void gemm2_kernel(
    const unsigned short* __restrict__ alignb, const unsigned short* __restrict__ WgT,
    const float* __restrict__ bg, const float* __restrict__ Ws,
    float* __restrict__ scores_part) {
  __shared__ unsigned short As[BM * BK];
  __shared__ unsigned short Bs[BN * BK];
  __shared__ float sred[BM * 2];
  int m0, n0, nt;
  tile_coords(blockIdx.x, m0, n0, nt);
  int t = threadIdx.x;
  f32x4 acc[4][4] = {};
  gemm_core<0>(alignb, WgT, m0, n0, t, As, Bs, acc);
  int lane = t & 63, wave = t >> 6, wr = wave >> 1, wc = wave & 1;
#pragma unroll
  for (int mi = 0; mi < 4; ++mi) {
#pragma unroll
    for (int j = 0; j < 4; ++j) {
      int rloc = wr * 64 + mi * 16 + ((lane >> 4) * 4) + j;
      int row = m0 + rloc;
      float p = 0.f;
#pragma unroll
      for (int ni = 0; ni < 4; ++ni) {
        int col = n0 + wc * 64 + ni * 16 + (lane & 15);
        float gp = acc[mi][ni][j] + bg[col];
        float gate = 1.f / (1.f + expf(-gp));
        float al = bf2f(alignb[(size_t)row * 1024 + col]);
        p += al * gate * Ws[col];
      }
      p += __shfl_xor(p, 1);
      p += __shfl_xor(p, 2);
      p += __shfl_xor(p, 4);
      p += __shfl_xor(p, 8);
      if ((lane & 15) == 0) sred[rloc * 2 + wc] = p;
    }
  }
  __syncthreads();
  if (t < 128) scores_part[(size_t)nt * 65536 + m0 + t] = sred[t * 2] + sred[t * 2 + 1];
}

// ---------- softmax over S=2048 per batch; writes weights output ----------
__global__ __launch_bounds__(256) void softmax_kernel(const float* __restrict__ sp,
                                                      float* __restrict__ wout) {
  __shared__ float red[256];
  int b = blockIdx.x, t = threadIdx.x;
  float sc[8];
  float lmax = -1e30f;
#pragma unroll
  for (int i = 0; i < 8; ++i) {
    int s = i * 256 + t;
    float v = 0.f;
#pragma unroll
    for (int n = 0; n < 8; ++n) v += sp[(size_t)n * 65536 + b * 2048 + s];
    sc[i] = v;
    lmax = fmaxf(lmax, v);
  }
  red[t] = lmax;
  __syncthreads();
  for (int off = 128; off > 0; off >>= 1) {
    if (t < off) red[t] = fmaxf(red[t], red[t + off]);
    __syncthreads();
  }
  float mx = red[0];
  __syncthreads();
  float lsum = 0.f;
#pragma unroll
  for (int i = 0; i < 8; ++i) {
    sc[i] = expf(sc[i] - mx);
    lsum += sc[i];
  }
  red[t] = lsum;
  __syncthreads();
  for (int off = 128; off > 0; off >>= 1) {
    if (t < off) red[t] += red[t + off];
    __syncthreads();
  }
  float inv = 1.f / red[0];
#pragma unroll
  for (int i = 0; i < 8; ++i) wout[(size_t)b * 2048 + i * 256 + t] = sc[i] * inv;
}

// ---------- context partials: ctx_part[sc,b,h] = sum_{s in chunk} w[b,s]*seq[b,s,h] ----------
__global__ __launch_bounds__(256) void context_kernel(const float* __restrict__ seq,
                                                      const float* __restrict__ wts,
                                                      float* __restrict__ ctx_part) {
  __shared__ float wsh[512];
  int b = blockIdx.x, h = blockIdx.y * 256 + threadIdx.x, s0 = blockIdx.z * 512;
  for (int i = threadIdx.x; i < 512; i += 256) wsh[i] = wts[(size_t)b * 2048 + s0 + i];
  __syncthreads();
  float acc = 0.f;
  const float* spp = seq + ((size_t)b * 2048 + s0) * 1024 + h;
#pragma unroll 4
  for (int s = 0; s < 512; ++s) acc += wsh[s] * spp[(size_t)s * 1024];
  ctx_part[(size_t)(blockIdx.z * 32 + b) * 1024 + h] = acc;
}

// ---------- pre partials: pre_part[kc,b,h] = sum_{k in chunk} fin[k]*Wo[k,h] ----------
__global__ __launch_bounds__(256) void pre_kernel(const float* __restrict__ ctx_part,
                                                  const float* __restrict__ q,
                                                  const float* __restrict__ Wo,
                                                  float* __restrict__ pre_part) {
  __shared__ float fin[256];
  int b = blockIdx.x, k0 = blockIdx.y * 256, t = threadIdx.x;
  int k = k0 + t;
  float f;
  if (k < 1024) {
    f = ctx_part[(size_t)(0 * 32 + b) * 1024 + k] + ctx_part[(size_t)(1 * 32 + b) * 1024 + k] +
        ctx_part[(size_t)(2 * 32 + b) * 1024 + k] + ctx_part[(size_t)(3 * 32 + b) * 1024 + k];
  } else {
    f = q[(size_t)b * 1024 + (k - 1024)];
  }
  fin[t] = f;
  __syncthreads();
  float a0 = 0.f, a1 = 0.f, a2 = 0.f, a3 = 0.f;
#pragma unroll 4
  for (int kk = 0; kk < 256; ++kk) {
    float fv = fin[kk];
    const float* wrow = Wo + (size_t)(k0 + kk) * 1024;
    a0 += fv * wrow[t];
    a1 += fv * wrow[t + 256];
    a2 += fv * wrow[t + 512];
    a3 += fv * wrow[t + 768];
  }
  float* dst = pre_part + (size_t)(blockIdx.y * 32 + b) * 1024;
  dst[t] = a0;
  dst[t + 256] = a1;
  dst[t + 512] = a2;
  dst[t + 768] = a3;
}

// ---------- final: pre = sum partials + bo + q (residual); layernorm -> fused out ----------
__global__ __launch_bounds__(256) void ln_kernel(const float* __restrict__ pre_part,
                                                 const float* __restrict__ q,
                                                 const float* __restrict__ bo,
                                                 const float* __restrict__ gamma,
                                                 const float* __restrict__ beta,
                                                 float* __restrict__ outF) {
  __shared__ float red[256];
  int b = blockIdx.x, t = threadIdx.x;
  float v[4];
  float lsum = 0.f;
#pragma unroll
  for (int i = 0; i < 4; ++i) {
    int h = i * 256 + t;
    float x = bo[h] + q[(size_t)b * 1024 + h];
#pragma unroll
    for (int kc = 0; kc < 8; ++kc) x += pre_part[(size_t)(kc * 32 + b) * 1024 + h];
    v[i] = x;
    lsum += x;
  }
  red[t] = lsum;
  __syncthreads();
  for (int off = 128; off > 0; off >>= 1) {
    if (t < off) red[t] += red[t + off];
    __syncthreads();
  }
  float mu = red[0] * (1.f / 1024.f);
  __syncthreads();
  float lv = 0.f;
#pragma unroll
  for (int i = 0; i < 4; ++i) {
    float d = v[i] - mu;
    lv += d * d;
  }
  red[t] = lv;
  __syncthreads();
  for (int off = 128; off > 0; off >>= 1) {
    if (t < off) red[t] += red[t + off];
    __syncthreads();
  }
  float var = red[0] * (1.f / 1024.f);
  float rs = rsqrtf(var + 1e-5f);
#pragma unroll
  for (int i = 0; i < 4; ++i) {
    int h = i * 256 + t;
    outF[(size_t)b * 1024 + h] = (v[i] - mu) * rs * gamma[h] + beta[h];
  }
}

// ---------- host ----------
extern "C" void kernel_launch(void* const* d_in, const int* in_sizes, int n_in,
                              void* d_out, int out_size, void* d_ws, size_t ws_size,
                              hipStream_t stream) {
  const float* seq = (const float*)d_in[0];
  const float* q = (const float*)d_in[1];
  const float* Wk = (const float*)d_in[2];
  const float* bk = (const float*)d_in[3];
  const float* Wq = (const float*)d_in[4];
  const float* bq = (const float*)d_in[5];
  const float* Wg = (const float*)d_in[6];
  const float* bg = (const float*)d_in[7];
  const float* Ws = (const float*)d_in[8];
  // d_in[9] = bs: softmax is shift-invariant, cancels everywhere it appears
  const float* Wo = (const float*)d_in[10];
  const float* bo = (const float*)d_in[11];
  const float* gamma = (const float*)d_in[12];
  const float* beta = (const float*)d_in[13];

  float* outF = (float*)d_out;         // fused [32,1024]
  float* outW = outF + 32 * 1024;      // weights [32,2048]

  char* ws = (char*)d_ws;
  unsigned short* alignb = (unsigned short*)ws;  ws += (size_t)134217728;  // [65536,1024] bf16
  unsigned short* WkT = (unsigned short*)ws;     ws += 2097152;            // [1024,1024] bf16
  unsigned short* WgT = (unsigned short*)ws;     ws += 2097152;
  float* qb = (float*)ws;                        ws += 131072;             // [32,1024]
  float* scores_part = (float*)ws;               ws += 2097152;            // [8,65536]
  float* ctx_part = (float*)ws;                  ws += 524288;             // [4,32,1024]
  float* pre_part = (float*)ws;                  ws += 1048576;            // [8,32,1024]
  if (ws_size < (size_t)(ws - (char*)d_ws)) return;  // insufficient scratch

  transpose_kernel<<<512, 256, 0, stream>>>(Wk, Wg, WkT, WgT);
  query_kernel<<<dim3(32, 4), 256, 0, stream>>>(q, Wq, bq, bk, qb);
  gemm1_kernel<<<4096, 256, 0, stream>>>(seq, WkT, qb, alignb);
  gemm2_kernel<<<4096, 256, 0, stream>>>(alignb, WgT, bg, Ws, scores_part);
  softmax_kernel<<<32, 256, 0, stream>>>(scores_part, outW);
  context_kernel<<<dim3(32, 4, 4), 256, 0, stream>>>(seq, outW, ctx_part);
  pre_kernel<<<dim3(32, 8), 256, 0, stream>>>(ctx_part, q, Wo, pre_part);
  ln_kernel<<<32, 256, 0, stream>>>(pre_part, q, bo, gamma, beta, outF);
}

// Round 2
// 718.476 us; speedup vs baseline: 1.0923x; 1.0923x over previous
//
#include <hip/hip_runtime.h>

typedef __attribute__((ext_vector_type(8))) short bf16x8;
typedef __attribute__((ext_vector_type(8))) unsigned short ushort8;
typedef __attribute__((ext_vector_type(4))) float f32x4;

#define BM 256
#define BN 256
#define BK 64

// ---------- helpers ----------
__device__ __forceinline__ unsigned short f2bf(float f) {
  union { float f; unsigned u; } c; c.f = f;
  return (unsigned short)((c.u + 0x7fffu + ((c.u >> 16) & 1u)) >> 16);  // RNE
}
__device__ __forceinline__ float bf2f(unsigned short u) {
  union { unsigned u; float f; } c; c.u = ((unsigned)u) << 16;
  return c.f;
}
__device__ __forceinline__ void gload16(const void* g, void* lds) {
  __builtin_amdgcn_global_load_lds(
      (const __attribute__((address_space(1))) unsigned int*)g,
      (__attribute__((address_space(3))) unsigned int*)lds, 16, 0, 0);
}

// stage a 256x64 bf16 tile (row-major, K contiguous) into LDS via global_load_lds.
// LDS layout: [row][8 slots of 16B], slot XOR-swizzled by (row&7); linear dest,
// inverse-swizzled source (rule #21).
__device__ __forceinline__ void stage_bf16(const unsigned short* __restrict__ src,
                                           unsigned short* dstLds, int row0, int k0, int t) {
#pragma unroll
  for (int r = 0; r < 4; ++r) {
    int c = r * 512 + t;
    int m = c >> 3, s = c & 7;
    int sg = s ^ (m & 7);
    gload16(src + (size_t)(row0 + m) * 1024 + k0 + sg * 8, (char*)dstLds + c * 16);
  }
}

// one BK=64 compute step: 64 MFMA per wave (8m x 4n x 2kk)
__device__ __forceinline__ void compute64(const unsigned short* As, const unsigned short* Bs,
                                          int lane, int wr, int wc, f32x4 (&acc)[8][4]) {
#pragma unroll
  for (int kk = 0; kk < 2; ++kk) {
    bf16x8 av[8], bv[4];
#pragma unroll
    for (int mi = 0; mi < 8; ++mi) {
      int ml = wr * 128 + mi * 16 + (lane & 15);
      int sl = (kk * 4 + (lane >> 4)) ^ (ml & 7);
      av[mi] = *(const bf16x8*)((const char*)As + ml * 128 + sl * 16);
    }
#pragma unroll
    for (int ni = 0; ni < 4; ++ni) {
      int nl = wc * 64 + ni * 16 + (lane & 15);
      int sl = (kk * 4 + (lane >> 4)) ^ (nl & 7);
      bv[ni] = *(const bf16x8*)((const char*)Bs + nl * 128 + sl * 16);
    }
#pragma unroll
    for (int mi = 0; mi < 8; ++mi)
#pragma unroll
      for (int ni = 0; ni < 4; ++ni)
        acc[mi][ni] =
            __builtin_amdgcn_mfma_f32_16x16x32_bf16(av[mi], bv[ni], acc[mi][ni], 0, 0, 0);
  }
}

__device__ __forceinline__ void tile_coords(int bid, int& m0, int& n0, int& nt) {
  // 1024 blocks, 8 XCDs, bijective; nt fastest within an XCD for A-panel L2 reuse
  int lin = (bid & 7) * 128 + (bid >> 3);
  int mt = lin >> 2;
  nt = lin & 3;
  m0 = mt * BM;
  n0 = nt * BN;
}

// ---------- prep: transpose+convert Wk, Wg (fp32 [H,A] -> bf16 [A,H]) ----------
__global__ __launch_bounds__(256) void transpose_kernel(
    const float* __restrict__ Wk, const float* __restrict__ Wg,
    unsigned short* __restrict__ WkT, unsigned short* __restrict__ WgT) {
  __shared__ float tile[64][65];
  int bid = blockIdx.x;
  int mat = bid >> 8;
  int tid = bid & 255;
  int tr = tid >> 4, tc = tid & 15;
  const float* src = mat ? Wg : Wk;
  unsigned short* dst = mat ? WgT : WkT;
  int r0 = tr * 64, c0 = tc * 64;
  int t = threadIdx.x;
  int lr = t >> 6, lc = t & 63;
#pragma unroll
  for (int i = 0; i < 16; ++i) {
    int r = i * 4 + lr;
    tile[r][lc] = src[(size_t)(r0 + r) * 1024 + c0 + lc];
  }
  __syncthreads();
#pragma unroll
  for (int i = 0; i < 16; ++i) {
    int r = i * 4 + lr;
    dst[(size_t)(c0 + r) * 1024 + r0 + lc] = f2bf(tile[lc][r]);
  }
}

// ---------- prep: qb[b,a] = q[b]·Wq[:,a] + bq[a] + bk[a] ----------
__global__ __launch_bounds__(256) void query_kernel(
    const float* __restrict__ q, const float* __restrict__ Wq,
    const float* __restrict__ bq, const float* __restrict__ bk,
    float* __restrict__ qb) {
  __shared__ float qs[1024];
  int b = blockIdx.x, a0 = blockIdx.y * 256, t = threadIdx.x;
#pragma unroll
  for (int i = 0; i < 4; ++i) qs[i * 256 + t] = q[(size_t)b * 1024 + i * 256 + t];
  __syncthreads();
  int a = a0 + t;
  float acc = bq[a] + bk[a];
#pragma unroll 4
  for (int h = 0; h < 1024; ++h) acc += qs[h] * Wq[(size_t)h * 1024 + a];
  qb[(size_t)b * 1024 + a] = acc;
}

// ---------- GEMM1: align = tanh(seq@Wk + bk + query) -> bf16 ----------
// A = seq fp32 (T14 async reg-staging: loads issued before compute, cvt+ds_write after)
__global__ __launch_bounds__(512, 2) void gemm1_kernel(
    const float* __restrict__ seq, const unsigned short* __restrict__ WkT,
    const float* __restrict__ qb, unsigned short* __restrict__ alignb) {
  __shared__ unsigned short As[2][BM * BK];
  __shared__ unsigned short Bs[2][BN * BK];
  int m0, n0, nt;
  tile_coords(blockIdx.x, m0, n0, nt);
  int t = threadIdx.x;
  int lane = t & 63, wave = t >> 6;
  int wr = wave >> 2, wc = wave & 3;
  f32x4 acc[8][4] = {};
  f32x4 ra0[4], ra1[4];

  // prologue: tile 0
#pragma unroll
  for (int r = 0; r < 4; ++r) {
    int c = r * 512 + t;
    int m = c >> 3, s = c & 7;
    const float* gp = seq + (size_t)(m0 + m) * 1024 + 0 + s * 8;
    ra0[r] = *(const f32x4*)gp;
    ra1[r] = *(const f32x4*)(gp + 4);
  }
  stage_bf16(WkT, Bs[0], n0, 0, t);
#pragma unroll
  for (int r = 0; r < 4; ++r) {
    int c = r * 512 + t;
    int m = c >> 3, s = c & 7;
    ushort8 o;
#pragma unroll
    for (int k = 0; k < 4; ++k) { o[k] = f2bf(ra0[r][k]); o[k + 4] = f2bf(ra1[r][k]); }
    *(ushort8*)((char*)As[0] + m * 128 + ((s ^ (m & 7)) * 16)) = o;
  }
  __syncthreads();

  for (int kt = 0; kt < 16; ++kt) {
    int cur = kt & 1, nxt = cur ^ 1;
    if (kt < 15) {
      int k0 = (kt + 1) * 64;
#pragma unroll
      for (int r = 0; r < 4; ++r) {
        int c = r * 512 + t;
        int m = c >> 3, s = c & 7;
        const float* gp = seq + (size_t)(m0 + m) * 1024 + k0 + s * 8;
        ra0[r] = *(const f32x4*)gp;
        ra1[r] = *(const f32x4*)(gp + 4);
      }
      stage_bf16(WkT, Bs[nxt], n0, k0, t);
    }
    compute64(As[cur], Bs[cur], lane, wr, wc, acc);
    if (kt < 15) {
#pragma unroll
      for (int r = 0; r < 4; ++r) {
        int c = r * 512 + t;
        int m = c >> 3, s = c & 7;
        ushort8 o;
#pragma unroll
        for (int k = 0; k < 4; ++k) { o[k] = f2bf(ra0[r][k]); o[k + 4] = f2bf(ra1[r][k]); }
        *(ushort8*)((char*)As[nxt] + m * 128 + ((s ^ (m & 7)) * 16)) = o;
      }
    }
    __syncthreads();
  }

  // epilogue: tanh(acc + query), store bf16
  const float* qrow = qb + (size_t)(m0 >> 11) * 1024;
#pragma unroll
  for (int mi = 0; mi < 8; ++mi) {
    int row0 = m0 + wr * 128 + mi * 16 + ((lane >> 4) * 4);
#pragma unroll
    for (int ni = 0; ni < 4; ++ni) {
      int col = n0 + wc * 64 + ni * 16 + (lane & 15);
      float qv = qrow[col];
#pragma unroll
      for (int j = 0; j < 4; ++j) {
        float v = tanhf(acc[mi][ni][j] + qv);
        alignb[(size_t)(row0 + j) * 1024 + col] = f2bf(v);
      }
    }
  }
}

// ---------- GEMM2: scores_part[nt,row] = sum_col align*sigmoid(align@Wg+bg)*Ws ----------
__global__ __launch_bounds__(512, 2) void gemm2_kernel(
    const unsigned short* __restrict__ alignb, const unsigned short* __restrict__ WgT,
    const float* __restrict__ bg, const float* __restrict__ Ws,
    float* __restrict__ scores_part) {
  __shared__ unsigned short As[2][BM * BK];
  __shared__ unsigned short Bs[2][BN * BK];
  __shared__ float sred[BM * 4];
  int m0, n0, nt;
  tile_coords(blockIdx.x, m0, n0, nt);
  int t = threadIdx.x;
  int lane = t & 63, wave = t >> 6;
  int wr = wave >> 2, wc = wave & 3;
  f32x4 acc[8][4] = {};

  stage_bf16(alignb, As[0], m0, 0, t);
  stage_bf16(WgT, Bs[0], n0, 0, t);
  __syncthreads();
  for (int kt = 0; kt < 16; ++kt) {
    int cur = kt & 1, nxt = cur ^ 1;
    if (kt < 15) {
      int k0 = (kt + 1) * 64;
      stage_bf16(alignb, As[nxt], m0, k0, t);
      stage_bf16(WgT, Bs[nxt], n0, k0, t);
    }
    compute64(As[cur], Bs[cur], lane, wr, wc, acc);
    __syncthreads();
  }

  // epilogue: gate + weighted row-reduction
#pragma unroll
  for (int mi = 0; mi < 8; ++mi) {
#pragma unroll
    for (int j = 0; j < 4; ++j) {
      int rloc = wr * 128 + mi * 16 + ((lane >> 4) * 4) + j;
      int row = m0 + rloc;
      float p = 0.f;
#pragma unroll
      for (int ni = 0; ni < 4; ++ni) {
        int col = n0 + wc * 64 + ni * 16 + (lane & 15);
        float gp = acc[mi][ni][j] + bg[col];
        float gate = 1.f / (1.f + expf(-gp));
        float al = bf2f(alignb[(size_t)row * 1024 + col]);
        p += al * gate * Ws[col];
      }
      p += __shfl_xor(p, 1);
      p += __shfl_xor(p, 2);
      p += __shfl_xor(p, 4);
      p += __shfl_xor(p, 8);
      if ((lane & 15) == 0) sred[rloc * 4 + wc] = p;
    }
  }
  __syncthreads();
  if (t < 256)
    scores_part[(size_t)nt * 65536 + m0 + t] =
        sred[t * 4] + sred[t * 4 + 1] + sred[t * 4 + 2] + sred[t * 4 + 3];
}

// ---------- softmax over S=2048 per batch; writes weights output ----------
__global__ __launch_bounds__(256) void softmax_kernel(const float* __restrict__ sp,
                                                      float* __restrict__ wout) {
  __shared__ float red[256];
  int b = blockIdx.x, t = threadIdx.x;
  float sc[8];
  float lmax = -1e30f;
#pragma unroll
  for (int i = 0; i < 8; ++i) {
    int s = i * 256 + t;
    float v = 0.f;
#pragma unroll
    for (int n = 0; n < 4; ++n) v += sp[(size_t)n * 65536 + b * 2048 + s];
    sc[i] = v;
    lmax = fmaxf(lmax, v);
  }
  red[t] = lmax;
  __syncthreads();
  for (int off = 128; off > 0; off >>= 1) {
    if (t < off) red[t] = fmaxf(red[t], red[t + off]);
    __syncthreads();
  }
  float mx = red[0];
  __syncthreads();
  float lsum = 0.f;
#pragma unroll
  for (int i = 0; i < 8; ++i) {
    sc[i] = expf(sc[i] - mx);
    lsum += sc[i];
  }
  red[t] = lsum;
  __syncthreads();
  for (int off = 128; off > 0; off >>= 1) {
    if (t < off) red[t] += red[t + off];
    __syncthreads();
  }
  float inv = 1.f / red[0];
#pragma unroll
  for (int i = 0; i < 8; ++i) wout[(size_t)b * 2048 + i * 256 + t] = sc[i] * inv;
}

// ---------- context partials ----------
__global__ __launch_bounds__(256) void context_kernel(const float* __restrict__ seq,
                                                      const float* __restrict__ wts,
                                                      float* __restrict__ ctx_part) {
  __shared__ float wsh[512];
  int b = blockIdx.x, h = blockIdx.y * 256 + threadIdx.x, s0 = blockIdx.z * 512;
  for (int i = threadIdx.x; i < 512; i += 256) wsh[i] = wts[(size_t)b * 2048 + s0 + i];
  __syncthreads();
  float acc = 0.f;
  const float* spp = seq + ((size_t)b * 2048 + s0) * 1024 + h;
#pragma unroll 4
  for (int s = 0; s < 512; ++s) acc += wsh[s] * spp[(size_t)s * 1024];
  ctx_part[(size_t)(blockIdx.z * 32 + b) * 1024 + h] = acc;
}

// ---------- pre partials: pre_part[kc,b,h] = sum_{k in chunk} fin[k]*Wo[k,h] ----------
__global__ __launch_bounds__(256) void pre_kernel(const float* __restrict__ ctx_part,
                                                  const float* __restrict__ q,
                                                  const float* __restrict__ Wo,
                                                  float* __restrict__ pre_part) {
  __shared__ float fin[256];
  int b = blockIdx.x, k0 = blockIdx.y * 256, t = threadIdx.x;
  int k = k0 + t;
  float f;
  if (k < 1024) {
    f = ctx_part[(size_t)(0 * 32 + b) * 1024 + k] + ctx_part[(size_t)(1 * 32 + b) * 1024 + k] +
        ctx_part[(size_t)(2 * 32 + b) * 1024 + k] + ctx_part[(size_t)(3 * 32 + b) * 1024 + k];
  } else {
    f = q[(size_t)b * 1024 + (k - 1024)];
  }
  fin[t] = f;
  __syncthreads();
  float a0 = 0.f, a1 = 0.f, a2 = 0.f, a3 = 0.f;
#pragma unroll 4
  for (int kk = 0; kk < 256; ++kk) {
    float fv = fin[kk];
    const float* wrow = Wo + (size_t)(k0 + kk) * 1024;
    a0 += fv * wrow[t];
    a1 += fv * wrow[t + 256];
    a2 += fv * wrow[t + 512];
    a3 += fv * wrow[t + 768];
  }
  float* dst = pre_part + (size_t)(blockIdx.y * 32 + b) * 1024;
  dst[t] = a0;
  dst[t + 256] = a1;
  dst[t + 512] = a2;
  dst[t + 768] = a3;
}

// ---------- final: residual + layernorm ----------
__global__ __launch_bounds__(256) void ln_kernel(const float* __restrict__ pre_part,
                                                 const float* __restrict__ q,
                                                 const float* __restrict__ bo,
                                                 const float* __restrict__ gamma,
                                                 const float* __restrict__ beta,
                                                 float* __restrict__ outF) {
  __shared__ float red[256];
  int b = blockIdx.x, t = threadIdx.x;
  float v[4];
  float lsum = 0.f;
#pragma unroll
  for (int i = 0; i < 4; ++i) {
    int h = i * 256 + t;
    float x = bo[h] + q[(size_t)b * 1024 + h];
#pragma unroll
    for (int kc = 0; kc < 8; ++kc) x += pre_part[(size_t)(kc * 32 + b) * 1024 + h];
    v[i] = x;
    lsum += x;
  }
  red[t] = lsum;
  __syncthreads();
  for (int off = 128; off > 0; off >>= 1) {
    if (t < off) red[t] += red[t + off];
    __syncthreads();
  }
  float mu = red[0] * (1.f / 1024.f);
  __syncthreads();
  float lv = 0.f;
#pragma unroll
  for (int i = 0; i < 4; ++i) {
    float d = v[i] - mu;
    lv += d * d;
  }
  red[t] = lv;
  __syncthreads();
  for (int off = 128; off > 0; off >>= 1) {
    if (t < off) red[t] += red[t + off];
    __syncthreads();
  }
  float var = red[0] * (1.f / 1024.f);
  float rs = rsqrtf(var + 1e-5f);
#pragma unroll
  for (int i = 0; i < 4; ++i) {
    int h = i * 256 + t;
    outF[(size_t)b * 1024 + h] = (v[i] - mu) * rs * gamma[h] + beta[h];
  }
}

// ---------- host ----------
extern "C" void kernel_launch(void* const* d_in, const int* in_sizes, int n_in,
                              void* d_out, int out_size, void* d_ws, size_t ws_size,
                              hipStream_t stream) {
  const float* seq = (const float*)d_in[0];
  const float* q = (const float*)d_in[1];
  const float* Wk = (const float*)d_in[2];
  const float* bk = (const float*)d_in[3];
  const float* Wq = (const float*)d_in[4];
  const float* bq = (const float*)d_in[5];
  const float* Wg = (const float*)d_in[6];
  const float* bg = (const float*)d_in[7];
  const float* Ws = (const float*)d_in[8];
  // d_in[9] = bs: softmax is shift-invariant, cancels everywhere it appears
  const float* Wo = (const float*)d_in[10];
  const float* bo = (const float*)d_in[11];
  const float* gamma = (const float*)d_in[12];
  const float* beta = (const float*)d_in[13];

  float* outF = (float*)d_out;         // fused [32,1024]
  float* outW = outF + 32 * 1024;      // weights [32,2048]

  char* ws = (char*)d_ws;
  unsigned short* alignb = (unsigned short*)ws;  ws += (size_t)134217728;  // [65536,1024] bf16
  unsigned short* WkT = (unsigned short*)ws;     ws += 2097152;            // [1024,1024] bf16
  unsigned short* WgT = (unsigned short*)ws;     ws += 2097152;
  float* qb = (float*)ws;                        ws += 131072;             // [32,1024]
  float* scores_part = (float*)ws;               ws += 1048576;            // [4,65536]
  float* ctx_part = (float*)ws;                  ws += 524288;             // [4,32,1024]
  float* pre_part = (float*)ws;                  ws += 1048576;            // [8,32,1024]
  if (ws_size < (size_t)(ws - (char*)d_ws)) return;  // insufficient scratch

  transpose_kernel<<<512, 256, 0, stream>>>(Wk, Wg, WkT, WgT);
  query_kernel<<<dim3(32, 4), 256, 0, stream>>>(q, Wq, bq, bk, qb);
  gemm1_kernel<<<1024, 512, 0, stream>>>(seq, WkT, qb, alignb);
  gemm2_kernel<<<1024, 512, 0, stream>>>(alignb, WgT, bg, Ws, scores_part);
  softmax_kernel<<<32, 256, 0, stream>>>(scores_part, outW);
  context_kernel<<<dim3(32, 4, 4), 256, 0, stream>>>(seq, outW, ctx_part);
  pre_kernel<<<dim3(32, 8), 256, 0, stream>>>(ctx_part, q, Wo, pre_part);
  ln_kernel<<<32, 256, 0, stream>>>(pre_part, q, bo, gamma, beta, outF);
}

// Round 3
// 695.119 us; speedup vs baseline: 1.1290x; 1.0336x over previous
//
#include <hip/hip_runtime.h>

typedef __attribute__((ext_vector_type(8))) short bf16x8;
typedef __attribute__((ext_vector_type(8))) unsigned short ushort8;
typedef __attribute__((ext_vector_type(4))) unsigned short ushortx4;
typedef __attribute__((ext_vector_type(4))) float f32x4;

#define BM 256
#define BN 256
#define BK 64

// ---------- helpers ----------
__device__ __forceinline__ unsigned short f2bf(float f) {
  union { float f; unsigned u; } c; c.f = f;
  return (unsigned short)((c.u + 0x7fffu + ((c.u >> 16) & 1u)) >> 16);  // RNE
}
__device__ __forceinline__ float bf2f(unsigned short u) {
  union { unsigned u; float f; } c; c.u = ((unsigned)u) << 16;
  return c.f;
}
__device__ __forceinline__ void gload16(const void* g, void* lds) {
  __builtin_amdgcn_global_load_lds(
      (const __attribute__((address_space(1))) unsigned int*)g,
      (__attribute__((address_space(3))) unsigned int*)lds, 16, 0, 0);
}
// raw barrier with compiler memory fences (s_barrier intrinsic is IntrNoMem —
// must stop the compiler moving LDS/VMEM ops across it ourselves)
__device__ __forceinline__ void bar() {
  asm volatile("" ::: "memory");
  __builtin_amdgcn_s_barrier();
  asm volatile("" ::: "memory");
}

// stage one 128-row half-tile (half in {0,1}) of a [256 x 64] bf16 K-tile.
// LDS: [row][8 slots of 16B], slot ^= row&7 swizzle; linear dest + inverse-swz source.
__device__ __forceinline__ void stage_half(const unsigned short* __restrict__ src,
                                           int row0, int k0, int half,
                                           unsigned short* buf, int t) {
#pragma unroll
  for (int r = 0; r < 2; ++r) {
    int c = r * 512 + t;                // [0,1024) 16B chunks of this half
    int ml = half * 128 + (c >> 3);     // row within 256-row tile
    int s = c & 7;
    int sg = s ^ (ml & 7);
    gload16(src + (size_t)(row0 + ml) * 1024 + k0 + sg * 8,
            (char*)buf + half * 16384 + c * 16);
  }
}

__device__ __forceinline__ void read_av(const unsigned short* buf, int qm, int lane, int wr,
                                        bf16x8 (&av)[2][4]) {
#pragma unroll
  for (int kk = 0; kk < 2; ++kk) {
    int sl = (kk * 4 + (lane >> 4)) ^ (lane & 7);
#pragma unroll
    for (int i = 0; i < 4; ++i) {
      int ml = wr * 128 + qm * 64 + i * 16 + (lane & 15);
      av[kk][i] = *(const bf16x8*)((const char*)buf + ml * 128 + sl * 16);
    }
  }
}
__device__ __forceinline__ void read_bv(const unsigned short* buf, int qn, int lane, int wc,
                                        bf16x8 (&bv)[2][2]) {
#pragma unroll
  for (int kk = 0; kk < 2; ++kk) {
    int sl = (kk * 4 + (lane >> 4)) ^ (lane & 7);
#pragma unroll
    for (int j = 0; j < 2; ++j) {
      int nl = wc * 64 + qn * 32 + j * 16 + (lane & 15);
      bv[kk][j] = *(const bf16x8*)((const char*)buf + nl * 128 + sl * 16);
    }
  }
}

__device__ __forceinline__ void mfma_q(const bf16x8 (&av)[2][4], const bf16x8 (&bv)[2][2],
                                       int qm, int qn, f32x4 (&acc)[8][4]) {
  __builtin_amdgcn_s_setprio(1);
#pragma unroll
  for (int kk = 0; kk < 2; ++kk)
#pragma unroll
    for (int i = 0; i < 4; ++i)
#pragma unroll
      for (int j = 0; j < 2; ++j)
        acc[qm * 4 + i][qn * 2 + j] = __builtin_amdgcn_mfma_f32_16x16x32_bf16(
            av[kk][i], bv[kk][j], acc[qm * 4 + i][qn * 2 + j], 0, 0, 0);
  __builtin_amdgcn_s_setprio(0);
}

// One K-tile = 4 phases (quadrants 00,01,11,10), one half-tile staged per phase,
// single counted vmcnt(2) at phase 4. Stage schedule (steady state, K-tile t):
//   ph1: A(t+1)h1 -> nxt   ph2: B(t+1)h0 -> nxt   ph3: B(t+1)h1 -> nxt
//   ph4: A(t+2)h0 -> cur (safe: cur's A last ds_read is ph3, barriers passed)
// vmcnt(2) at ph4 retires all of K(t+1)'s 4 half-tiles, leaves A(t+2)h0 in flight.
__device__ __forceinline__ void ktile(const unsigned short* __restrict__ Ag,
                                      const unsigned short* __restrict__ Bg,
                                      int m0, int n0, int t, int lane, int wr, int wc,
                                      unsigned short* curA, unsigned short* curB,
                                      unsigned short* nxtA, unsigned short* nxtB,
                                      int k1, int k2, bool st1, bool st2, int wn,
                                      f32x4 (&acc)[8][4]) {
  bf16x8 av[2][4], bv0[2][2], bv1[2][2];
  // phase 1: (qm0, qn0)
  read_av(curA, 0, lane, wr, av);
  read_bv(curB, 0, lane, wc, bv0);
  if (st1) stage_half(Ag, m0, k1, 1, nxtA, t);
  bar();
  mfma_q(av, bv0, 0, 0, acc);
  bar();
  // phase 2: (qm0, qn1)
  read_bv(curB, 1, lane, wc, bv1);
  if (st1) stage_half(Bg, n0, k1, 0, nxtB, t);
  bar();
  mfma_q(av, bv1, 0, 1, acc);
  bar();
  // phase 3: (qm1, qn1)
  read_av(curA, 1, lane, wr, av);
  if (st1) stage_half(Bg, n0, k1, 1, nxtB, t);
  bar();
  mfma_q(av, bv1, 1, 1, acc);
  bar();
  // phase 4: (qm1, qn0)
  if (st2) stage_half(Ag, m0, k2, 0, curA, t);
  if (wn == 0) asm volatile("s_waitcnt vmcnt(0)" ::: "memory");
  else if (wn > 0) asm volatile("s_waitcnt vmcnt(2)" ::: "memory");
  bar();
  mfma_q(av, bv0, 1, 0, acc);
  bar();
}

#define GEMM_PIPELINE(Ag, Bg)                                                         \
  stage_half(Ag, m0, 0, 0, As0, t);                                                   \
  stage_half(Ag, m0, 0, 1, As0, t);                                                   \
  stage_half(Bg, n0, 0, 0, Bs0, t);                                                   \
  stage_half(Bg, n0, 0, 1, Bs0, t);                                                   \
  stage_half(Ag, m0, 64, 0, As1, t);                                                  \
  asm volatile("s_waitcnt vmcnt(2)" ::: "memory");                                    \
  bar();                                                                              \
  _Pragma("unroll 1") for (int kt = 0; kt < 16; kt += 2) {                            \
    bool nl = kt < 14;                                                                \
    ktile(Ag, Bg, m0, n0, t, lane, wr, wc, As0, Bs0, As1, Bs1, (kt + 1) * 64,         \
          (kt + 2) * 64, true, nl, nl ? 2 : 0, acc);                                  \
    ktile(Ag, Bg, m0, n0, t, lane, wr, wc, As1, Bs1, As0, Bs0, (kt + 2) * 64,         \
          (kt + 3) * 64, nl, nl, nl ? 2 : -1, acc);                                   \
  }

__device__ __forceinline__ void tile_coords(int bid, int& m0, int& n0, int& nt) {
  // 1024 blocks, 8 XCDs, bijective; nt fastest within an XCD for A-panel L2 reuse
  int lin = (bid & 7) * 128 + (bid >> 3);
  int mt = lin >> 2;
  nt = lin & 3;
  m0 = mt * BM;
  n0 = nt * BN;
}

// ---------- prep: seq fp32 -> bf16 ----------
__global__ __launch_bounds__(256) void convert_kernel(const float* __restrict__ in,
                                                      unsigned short* __restrict__ out) {
  size_t i = ((size_t)blockIdx.x * 256 + threadIdx.x) * 8;
  const size_t stride = (size_t)2048 * 256 * 8;
  for (; i < (size_t)67108864; i += stride) {
    f32x4 v0 = *(const f32x4*)(in + i);
    f32x4 v1 = *(const f32x4*)(in + i + 4);
    ushort8 o;
#pragma unroll
    for (int k = 0; k < 4; ++k) { o[k] = f2bf(v0[k]); o[k + 4] = f2bf(v1[k]); }
    *(ushort8*)(out + i) = o;
  }
}

// ---------- prep: transpose+convert Wk, Wg (fp32 [H,A] -> bf16 [A,H]) ----------
__global__ __launch_bounds__(256) void transpose_kernel(
    const float* __restrict__ Wk, const float* __restrict__ Wg,
    unsigned short* __restrict__ WkT, unsigned short* __restrict__ WgT) {
  __shared__ float tile[64][65];
  int bid = blockIdx.x;
  int mat = bid >> 8;
  int tid = bid & 255;
  int tr = tid >> 4, tc = tid & 15;
  const float* src = mat ? Wg : Wk;
  unsigned short* dst = mat ? WgT : WkT;
  int r0 = tr * 64, c0 = tc * 64;
  int t = threadIdx.x;
  int lr = t >> 6, lc = t & 63;
#pragma unroll
  for (int i = 0; i < 16; ++i) {
    int r = i * 4 + lr;
    tile[r][lc] = src[(size_t)(r0 + r) * 1024 + c0 + lc];
  }
  __syncthreads();
#pragma unroll
  for (int i = 0; i < 16; ++i) {
    int r = i * 4 + lr;
    dst[(size_t)(c0 + r) * 1024 + r0 + lc] = f2bf(tile[lc][r]);
  }
}

// ---------- prep: qb[b,a] = q[b]·Wq[:,a] + bq[a] + bk[a] ----------
__global__ __launch_bounds__(256) void query_kernel(
    const float* __restrict__ q, const float* __restrict__ Wq,
    const float* __restrict__ bq, const float* __restrict__ bk,
    float* __restrict__ qb) {
  __shared__ float qs[1024];
  int b = blockIdx.x, a0 = blockIdx.y * 256, t = threadIdx.x;
#pragma unroll
  for (int i = 0; i < 4; ++i) qs[i * 256 + t] = q[(size_t)b * 1024 + i * 256 + t];
  __syncthreads();
  int a = a0 + t;
  float acc = bq[a] + bk[a];
#pragma unroll 4
  for (int h = 0; h < 1024; ++h) acc += qs[h] * Wq[(size_t)h * 1024 + a];
  qb[(size_t)b * 1024 + a] = acc;
}

// ---------- GEMM1: align = tanh(seqb@WkT^T + query) -> bf16 ----------
__global__ __launch_bounds__(512, 2) void gemm1_kernel(
    const unsigned short* __restrict__ seqb, const unsigned short* __restrict__ WkT,
    const float* __restrict__ qb, unsigned short* __restrict__ alignb) {
  __shared__ unsigned short As0[BM * BK], Bs0[BN * BK], As1[BM * BK], Bs1[BN * BK];
  int m0, n0, nt;
  tile_coords(blockIdx.x, m0, n0, nt);
  int t = threadIdx.x, lane = t & 63, wave = t >> 6;
  int wr = wave >> 2, wc = wave & 3;
  f32x4 acc[8][4] = {};
  GEMM_PIPELINE(seqb, WkT)

  const float* qrow = qb + (size_t)(m0 >> 11) * 1024;  // 256-row tile stays in one batch
#pragma unroll
  for (int mi = 0; mi < 8; ++mi) {
    int row0 = m0 + wr * 128 + mi * 16 + ((lane >> 4) * 4);
#pragma unroll
    for (int ni = 0; ni < 4; ++ni) {
      int col = n0 + wc * 64 + ni * 16 + (lane & 15);
      float qv = qrow[col];
#pragma unroll
      for (int j = 0; j < 4; ++j) {
        float v = tanhf(acc[mi][ni][j] + qv);
        alignb[(size_t)(row0 + j) * 1024 + col] = f2bf(v);
      }
    }
  }
}

// ---------- GEMM2: scores_part[nt,row] = sum_col align*sigmoid(align@Wg+bg)*Ws ----------
__global__ __launch_bounds__(512, 2) void gemm2_kernel(
    const unsigned short* __restrict__ alignb, const unsigned short* __restrict__ WgT,
    const float* __restrict__ bg, const float* __restrict__ Ws,
    float* __restrict__ scores_part) {
  __shared__ unsigned short As0[BM * BK], Bs0[BN * BK], As1[BM * BK], Bs1[BN * BK];
  __shared__ float sred[BM * 4];
  int m0, n0, nt;
  tile_coords(blockIdx.x, m0, n0, nt);
  int t = threadIdx.x, lane = t & 63, wave = t >> 6;
  int wr = wave >> 2, wc = wave & 3;
  f32x4 acc[8][4] = {};
  GEMM_PIPELINE(alignb, WgT)

#pragma unroll
  for (int mi = 0; mi < 8; ++mi) {
#pragma unroll
    for (int j = 0; j < 4; ++j) {
      int rloc = wr * 128 + mi * 16 + ((lane >> 4) * 4) + j;
      int row = m0 + rloc;
      float p = 0.f;
#pragma unroll
      for (int ni = 0; ni < 4; ++ni) {
        int col = n0 + wc * 64 + ni * 16 + (lane & 15);
        float gp = acc[mi][ni][j] + bg[col];
        float gate = 1.f / (1.f + expf(-gp));
        float al = bf2f(alignb[(size_t)row * 1024 + col]);
        p += al * gate * Ws[col];
      }
      p += __shfl_xor(p, 1);
      p += __shfl_xor(p, 2);
      p += __shfl_xor(p, 4);
      p += __shfl_xor(p, 8);
      if ((lane & 15) == 0) sred[rloc * 4 + wc] = p;
    }
  }
  __syncthreads();
  if (t < 256)
    scores_part[(size_t)nt * 65536 + m0 + t] =
        sred[t * 4] + sred[t * 4 + 1] + sred[t * 4 + 2] + sred[t * 4 + 3];
}

// ---------- softmax over S=2048 per batch; writes weights output ----------
__global__ __launch_bounds__(256) void softmax_kernel(const float* __restrict__ sp,
                                                      float* __restrict__ wout) {
  __shared__ float red[256];
  int b = blockIdx.x, t = threadIdx.x;
  float sc[8];
  float lmax = -1e30f;
#pragma unroll
  for (int i = 0; i < 8; ++i) {
    int s = i * 256 + t;
    float v = 0.f;
#pragma unroll
    for (int n = 0; n < 4; ++n) v += sp[(size_t)n * 65536 + b * 2048 + s];
    sc[i] = v;
    lmax = fmaxf(lmax, v);
  }
  red[t] = lmax;
  __syncthreads();
  for (int off = 128; off > 0; off >>= 1) {
    if (t < off) red[t] = fmaxf(red[t], red[t + off]);
    __syncthreads();
  }
  float mx = red[0];
  __syncthreads();
  float lsum = 0.f;
#pragma unroll
  for (int i = 0; i < 8; ++i) {
    sc[i] = expf(sc[i] - mx);
    lsum += sc[i];
  }
  red[t] = lsum;
  __syncthreads();
  for (int off = 128; off > 0; off >>= 1) {
    if (t < off) red[t] += red[t + off];
    __syncthreads();
  }
  float inv = 1.f / red[0];
#pragma unroll
  for (int i = 0; i < 8; ++i) wout[(size_t)b * 2048 + i * 256 + t] = sc[i] * inv;
}

// ---------- context partials (bf16 seq read, 4 h per thread) ----------
__global__ __launch_bounds__(256) void context_kernel(const unsigned short* __restrict__ seqb,
                                                      const float* __restrict__ wts,
                                                      float* __restrict__ ctx_part) {
  __shared__ float wsh[512];
  int b = blockIdx.x, t = threadIdx.x, s0 = blockIdx.z * 512;
  int h0 = t * 4;
  for (int i = t; i < 512; i += 256) wsh[i] = wts[(size_t)b * 2048 + s0 + i];
  __syncthreads();
  float a0 = 0.f, a1 = 0.f, a2 = 0.f, a3 = 0.f;
  const unsigned short* p = seqb + ((size_t)b * 2048 + s0) * 1024 + h0;
#pragma unroll 4
  for (int s = 0; s < 512; ++s) {
    ushortx4 v = *(const ushortx4*)(p + (size_t)s * 1024);
    float w = wsh[s];
    a0 += w * bf2f(v[0]);
    a1 += w * bf2f(v[1]);
    a2 += w * bf2f(v[2]);
    a3 += w * bf2f(v[3]);
  }
  float* dst = ctx_part + (size_t)(blockIdx.z * 32 + b) * 1024 + h0;
  dst[0] = a0; dst[1] = a1; dst[2] = a2; dst[3] = a3;
}

// ---------- pre partials: pre_part[kc,b,h] = sum_{k in chunk} fin[k]*Wo[k,h] ----------
__global__ __launch_bounds__(256) void pre_kernel(const float* __restrict__ ctx_part,
                                                  const float* __restrict__ q,
                                                  const float* __restrict__ Wo,
                                                  float* __restrict__ pre_part) {
  __shared__ float fin[256];
  int b = blockIdx.x, k0 = blockIdx.y * 256, t = threadIdx.x;
  int k = k0 + t;
  float f;
  if (k < 1024) {
    f = ctx_part[(size_t)(0 * 32 + b) * 1024 + k] + ctx_part[(size_t)(1 * 32 + b) * 1024 + k] +
        ctx_part[(size_t)(2 * 32 + b) * 1024 + k] + ctx_part[(size_t)(3 * 32 + b) * 1024 + k];
  } else {
    f = q[(size_t)b * 1024 + (k - 1024)];
  }
  fin[t] = f;
  __syncthreads();
  float a0 = 0.f, a1 = 0.f, a2 = 0.f, a3 = 0.f;
#pragma unroll 4
  for (int kk = 0; kk < 256; ++kk) {
    float fv = fin[kk];
    const float* wrow = Wo + (size_t)(k0 + kk) * 1024;
    a0 += fv * wrow[t];
    a1 += fv * wrow[t + 256];
    a2 += fv * wrow[t + 512];
    a3 += fv * wrow[t + 768];
  }
  float* dst = pre_part + (size_t)(blockIdx.y * 32 + b) * 1024;
  dst[t] = a0;
  dst[t + 256] = a1;
  dst[t + 512] = a2;
  dst[t + 768] = a3;
}

// ---------- final: residual + layernorm ----------
__global__ __launch_bounds__(256) void ln_kernel(const float* __restrict__ pre_part,
                                                 const float* __restrict__ q,
                                                 const float* __restrict__ bo,
                                                 const float* __restrict__ gamma,
                                                 const float* __restrict__ beta,
                                                 float* __restrict__ outF) {
  __shared__ float red[256];
  int b = blockIdx.x, t = threadIdx.x;
  float v[4];
  float lsum = 0.f;
#pragma unroll
  for (int i = 0; i < 4; ++i) {
    int h = i * 256 + t;
    float x = bo[h] + q[(size_t)b * 1024 + h];
#pragma unroll
    for (int kc = 0; kc < 8; ++kc) x += pre_part[(size_t)(kc * 32 + b) * 1024 + h];
    v[i] = x;
    lsum += x;
  }
  red[t] = lsum;
  __syncthreads();
  for (int off = 128; off > 0; off >>= 1) {
    if (t < off) red[t] += red[t + off];
    __syncthreads();
  }
  float mu = red[0] * (1.f / 1024.f);
  __syncthreads();
  float lv = 0.f;
#pragma unroll
  for (int i = 0; i < 4; ++i) {
    float d = v[i] - mu;
    lv += d * d;
  }
  red[t] = lv;
  __syncthreads();
  for (int off = 128; off > 0; off >>= 1) {
    if (t < off) red[t] += red[t + off];
    __syncthreads();
  }
  float var = red[0] * (1.f / 1024.f);
  float rs = rsqrtf(var + 1e-5f);
#pragma unroll
  for (int i = 0; i < 4; ++i) {
    int h = i * 256 + t;
    outF[(size_t)b * 1024 + h] = (v[i] - mu) * rs * gamma[h] + beta[h];
  }
}

// ---------- host ----------
extern "C" void kernel_launch(void* const* d_in, const int* in_sizes, int n_in,
                              void* d_out, int out_size, void* d_ws, size_t ws_size,
                              hipStream_t stream) {
  const float* seq = (const float*)d_in[0];
  const float* q = (const float*)d_in[1];
  const float* Wk = (const float*)d_in[2];
  const float* bk = (const float*)d_in[3];
  const float* Wq = (const float*)d_in[4];
  const float* bq = (const float*)d_in[5];
  const float* Wg = (const float*)d_in[6];
  const float* bg = (const float*)d_in[7];
  const float* Ws = (const float*)d_in[8];
  // d_in[9] = bs: softmax is shift-invariant, cancels everywhere it appears
  const float* Wo = (const float*)d_in[10];
  const float* bo = (const float*)d_in[11];
  const float* gamma = (const float*)d_in[12];
  const float* beta = (const float*)d_in[13];

  float* outF = (float*)d_out;         // fused [32,1024]
  float* outW = outF + 32 * 1024;      // weights [32,2048]

  char* ws = (char*)d_ws;
  unsigned short* alignb = (unsigned short*)ws;  ws += (size_t)134217728;  // [65536,1024] bf16
  unsigned short* seqb = (unsigned short*)ws;    ws += (size_t)134217728;  // [65536,1024] bf16
  unsigned short* WkT = (unsigned short*)ws;     ws += 2097152;            // [1024,1024] bf16
  unsigned short* WgT = (unsigned short*)ws;     ws += 2097152;
  float* qb = (float*)ws;                        ws += 131072;             // [32,1024]
  float* scores_part = (float*)ws;               ws += 1048576;            // [4,65536]
  float* ctx_part = (float*)ws;                  ws += 524288;             // [4,32,1024]
  float* pre_part = (float*)ws;                  ws += 1048576;            // [8,32,1024]
  if (ws_size < (size_t)(ws - (char*)d_ws)) return;  // insufficient scratch

  convert_kernel<<<2048, 256, 0, stream>>>(seq, seqb);
  transpose_kernel<<<512, 256, 0, stream>>>(Wk, Wg, WkT, WgT);
  query_kernel<<<dim3(32, 4), 256, 0, stream>>>(q, Wq, bq, bk, qb);
  gemm1_kernel<<<1024, 512, 0, stream>>>(seqb, WkT, qb, alignb);
  gemm2_kernel<<<1024, 512, 0, stream>>>(alignb, WgT, bg, Ws, scores_part);
  softmax_kernel<<<32, 256, 0, stream>>>(scores_part, outW);
  context_kernel<<<dim3(32, 1, 4), 256, 0, stream>>>(seqb, outW, ctx_part);
  pre_kernel<<<dim3(32, 8), 256, 0, stream>>>(ctx_part, q, Wo, pre_part);
  ln_kernel<<<32, 256, 0, stream>>>(pre_part, q, bo, gamma, beta, outF);
}

// Round 4
// 657.268 us; speedup vs baseline: 1.1940x; 1.0576x over previous
//
#include <hip/hip_runtime.h>

typedef __attribute__((ext_vector_type(8))) short bf16x8;
typedef __attribute__((ext_vector_type(8))) unsigned short ushort8;
typedef __attribute__((ext_vector_type(4))) unsigned short ushortx4;
typedef __attribute__((ext_vector_type(4))) float f32x4;

#define BM 256
#define BN 256
#define BK 64

// ---------- helpers ----------
__device__ __forceinline__ unsigned short f2bf(float f) {
  union { float f; unsigned u; } c; c.f = f;
  return (unsigned short)((c.u + 0x7fffu + ((c.u >> 16) & 1u)) >> 16);  // RNE
}
__device__ __forceinline__ float bf2f(unsigned short u) {
  union { unsigned u; float f; } c; c.u = ((unsigned)u) << 16;
  return c.f;
}
__device__ __forceinline__ void gload16(const void* g, void* lds) {
  __builtin_amdgcn_global_load_lds(
      (const __attribute__((address_space(1))) unsigned int*)g,
      (__attribute__((address_space(3))) unsigned int*)lds, 16, 0, 0);
}
__device__ __forceinline__ void bar() {
  asm volatile("" ::: "memory");
  __builtin_amdgcn_s_barrier();
  asm volatile("" ::: "memory");
}
template <int N> __device__ __forceinline__ void vwait() {
  if constexpr (N == 10) asm volatile("s_waitcnt vmcnt(10)" ::: "memory");
  else if constexpr (N == 8) asm volatile("s_waitcnt vmcnt(8)" ::: "memory");
  else if constexpr (N == 4) asm volatile("s_waitcnt vmcnt(4)" ::: "memory");
  else if constexpr (N == 2) asm volatile("s_waitcnt vmcnt(2)" ::: "memory");
  else if constexpr (N == 0) asm volatile("s_waitcnt vmcnt(0)" ::: "memory");
}

// LDS row remap so each 128-row half is read by exactly one phase:
//   A: tile row m -> la = ((m>>6)&1)*128 + (m>>7)*64 + (m&63)   (half = qm)
//   B: tile col n -> lb = ((n>>5)&1)*128 + (n>>6)*32 + (n&31)   (half = qn)
// byte(l, slot s) = l*128 + (s ^ (l&7))*16 ; staged via inverse-swz global source.
__device__ __forceinline__ void stage_A(const unsigned short* __restrict__ src, int row0,
                                        int k0, int h, unsigned short* buf, int t) {
#pragma unroll
  for (int r = 0; r < 2; ++r) {
    int c = r * 512 + t;            // 16B chunk in [0,1024)
    int ll = c >> 3, s = c & 7;
    int sg = s ^ (ll & 7);
    int m = ((ll >> 6) << 7) + h * 64 + (ll & 63);
    gload16(src + (size_t)(row0 + m) * 1024 + k0 + sg * 8,
            (char*)buf + h * 16384 + c * 16);
  }
}
__device__ __forceinline__ void stage_B(const unsigned short* __restrict__ src, int col0,
                                        int k0, int h, unsigned short* buf, int t) {
#pragma unroll
  for (int r = 0; r < 2; ++r) {
    int c = r * 512 + t;
    int ll = c >> 3, s = c & 7;
    int sg = s ^ (ll & 7);
    int n = ((ll >> 5) << 6) + h * 32 + (ll & 31);
    gload16(src + (size_t)(col0 + n) * 1024 + k0 + sg * 8,
            (char*)buf + h * 16384 + c * 16);
  }
}

__device__ __forceinline__ void read_av(const unsigned short* buf, int qm, int lane, int wr,
                                        bf16x8 (&av)[2][4]) {
#pragma unroll
  for (int kk = 0; kk < 2; ++kk) {
    int sl = (kk * 4 + (lane >> 4)) ^ (lane & 7);
#pragma unroll
    for (int i = 0; i < 4; ++i) {
      int la = qm * 128 + wr * 64 + i * 16 + (lane & 15);
      av[kk][i] = *(const bf16x8*)((const char*)buf + la * 128 + sl * 16);
    }
  }
}
__device__ __forceinline__ void read_bv(const unsigned short* buf, int qn, int lane, int wc,
                                        bf16x8 (&bv)[2][2]) {
#pragma unroll
  for (int kk = 0; kk < 2; ++kk) {
    int sl = (kk * 4 + (lane >> 4)) ^ (lane & 7);
#pragma unroll
    for (int j = 0; j < 2; ++j) {
      int lb = qn * 128 + wc * 32 + j * 16 + (lane & 15);
      bv[kk][j] = *(const bf16x8*)((const char*)buf + lb * 128 + sl * 16);
    }
  }
}

__device__ __forceinline__ void mfma_q(const bf16x8 (&av)[2][4], const bf16x8 (&bv)[2][2],
                                       int qm, int qn, f32x4 (&acc)[8][4]) {
  __builtin_amdgcn_s_setprio(1);
#pragma unroll
  for (int kk = 0; kk < 2; ++kk)
#pragma unroll
    for (int i = 0; i < 4; ++i)
#pragma unroll
      for (int j = 0; j < 2; ++j)
        acc[qm * 4 + i][qn * 2 + j] = __builtin_amdgcn_mfma_f32_16x16x32_bf16(
            av[kk][i], bv[kk][j], acc[qm * 4 + i][qn * 2 + j], 0, 0, 0);
  __builtin_amdgcn_s_setprio(0);
}

// K-tile = 4 phases, quadrants (qm,qn) = (0,0),(0,1),(1,1),(1,0).
// Reads: ph1: A-h0 + B-h0; ph2: B-h1; ph3: A-h1; ph4: none (regs only).
// Rolling stages (into regions freed the previous phase):
//   ph1: A(t+1)h1 -> nxtA   ph2: A(t+2)h0 -> curA
//   ph3: B(t+2)h0 -> curB   ph4: B(t+2)h1 -> curB
// Counted waits before each barrier; steady state W=10 (5 stage-slots * 2 loads
// in flight past each needed half ~ 6 phases of prefetch depth > HBM latency).
template <int W1, int W2, int W3, bool S1, bool S2, bool S3, bool S4>
__device__ __forceinline__ void ktile(const unsigned short* __restrict__ Ag,
                                      const unsigned short* __restrict__ Bg,
                                      int m0, int n0, int t, int lane, int wr, int wc,
                                      unsigned short* curA, unsigned short* curB,
                                      unsigned short* nxtA, unsigned short* nxtB,
                                      int kA1, int kAB2, f32x4 (&acc)[8][4]) {
  bf16x8 av0[2][4], av1[2][4], bv0[2][2], bv1[2][2];
  // phase 1
  vwait<W1>();
  bar();
  read_av(curA, 0, lane, wr, av0);
  read_bv(curB, 0, lane, wc, bv0);
  if (S1) stage_A(Ag, m0, kA1, 1, nxtA, t);
  mfma_q(av0, bv0, 0, 0, acc);
  // phase 2
  vwait<W2>();
  bar();
  read_bv(curB, 1, lane, wc, bv1);
  if (S2) stage_A(Ag, m0, kAB2, 0, curA, t);
  mfma_q(av0, bv1, 0, 1, acc);
  // phase 3
  vwait<W3>();
  bar();
  read_av(curA, 1, lane, wr, av1);
  if (S3) stage_B(Bg, n0, kAB2, 0, curB, t);
  mfma_q(av1, bv1, 1, 1, acc);
  // phase 4 (no reads, no barrier needed: stage target freed 2 barriers ago)
  if (S4) stage_B(Bg, n0, kAB2, 1, curB, t);
  mfma_q(av1, bv0, 1, 0, acc);
}

// Prologue stages 7 halves in virtual-slot order; tiles 0..13 steady, 14/15 peeled.
#define GEMM_PIPELINE(Ag, Bg)                                                       \
  stage_A(Ag, m0, 0, 0, As0, t);                                                    \
  stage_B(Bg, n0, 0, 0, Bs0, t);                                                    \
  stage_B(Bg, n0, 0, 1, Bs0, t);                                                    \
  stage_A(Ag, m0, 0, 1, As0, t);                                                    \
  stage_A(Ag, m0, 64, 0, As1, t);                                                   \
  stage_B(Bg, n0, 64, 0, Bs1, t);                                                   \
  stage_B(Bg, n0, 64, 1, Bs1, t);                                                   \
  _Pragma("unroll 1") for (int kt = 0; kt < 14; kt += 2) {                          \
    ktile<10, 10, 10, true, true, true, true>(Ag, Bg, m0, n0, t, lane, wr, wc,      \
        As0, Bs0, As1, Bs1, (kt + 1) * 64, (kt + 2) * 64, acc);                     \
    ktile<10, 10, 10, true, true, true, true>(Ag, Bg, m0, n0, t, lane, wr, wc,      \
        As1, Bs1, As0, Bs0, (kt + 2) * 64, (kt + 3) * 64, acc);                     \
  }                                                                                 \
  ktile<10, 10, 8, true, false, false, false>(Ag, Bg, m0, n0, t, lane, wr, wc,      \
      As0, Bs0, As1, Bs1, 15 * 64, 0, acc);                                         \
  ktile<4, 2, 0, false, false, false, false>(Ag, Bg, m0, n0, t, lane, wr, wc,       \
      As1, Bs1, As0, Bs0, 0, 0, acc);

__device__ __forceinline__ void tile_coords(int bid, int& m0, int& n0, int& nt) {
  // 1024 blocks, 8 XCDs, bijective; nt fastest within an XCD for A-panel L2 reuse
  int lin = (bid & 7) * 128 + (bid >> 3);
  int mt = lin >> 2;
  nt = lin & 3;
  m0 = mt * BM;
  n0 = nt * BN;
}

// ---------- prep: seq fp32 -> bf16 ----------
__global__ __launch_bounds__(256) void convert_kernel(const float* __restrict__ in,
                                                      unsigned short* __restrict__ out) {
  size_t i = ((size_t)blockIdx.x * 256 + threadIdx.x) * 8;
  const size_t stride = (size_t)2048 * 256 * 8;
  for (; i < (size_t)67108864; i += stride) {
    f32x4 v0 = *(const f32x4*)(in + i);
    f32x4 v1 = *(const f32x4*)(in + i + 4);
    ushort8 o;
#pragma unroll
    for (int k = 0; k < 4; ++k) { o[k] = f2bf(v0[k]); o[k + 4] = f2bf(v1[k]); }
    *(ushort8*)(out + i) = o;
  }
}

// ---------- prep: transpose+convert Wk, Wg (fp32 [H,A] -> bf16 [A,H]) ----------
__global__ __launch_bounds__(256) void transpose_kernel(
    const float* __restrict__ Wk, const float* __restrict__ Wg,
    unsigned short* __restrict__ WkT, unsigned short* __restrict__ WgT) {
  __shared__ float tile[64][65];
  int bid = blockIdx.x;
  int mat = bid >> 8;
  int tid = bid & 255;
  int tr = tid >> 4, tc = tid & 15;
  const float* src = mat ? Wg : Wk;
  unsigned short* dst = mat ? WgT : WkT;
  int r0 = tr * 64, c0 = tc * 64;
  int t = threadIdx.x;
  int lr = t >> 6, lc = t & 63;
#pragma unroll
  for (int i = 0; i < 16; ++i) {
    int r = i * 4 + lr;
    tile[r][lc] = src[(size_t)(r0 + r) * 1024 + c0 + lc];
  }
  __syncthreads();
#pragma unroll
  for (int i = 0; i < 16; ++i) {
    int r = i * 4 + lr;
    dst[(size_t)(c0 + r) * 1024 + r0 + lc] = f2bf(tile[lc][r]);
  }
}

// ---------- prep: qb[b,a] = q[b]·Wq[:,a] + bq[a] + bk[a] ----------
__global__ __launch_bounds__(256) void query_kernel(
    const float* __restrict__ q, const float* __restrict__ Wq,
    const float* __restrict__ bq, const float* __restrict__ bk,
    float* __restrict__ qb) {
  __shared__ float qs[1024];
  int b = blockIdx.x, a0 = blockIdx.y * 256, t = threadIdx.x;
#pragma unroll
  for (int i = 0; i < 4; ++i) qs[i * 256 + t] = q[(size_t)b * 1024 + i * 256 + t];
  __syncthreads();
  int a = a0 + t;
  float acc = bq[a] + bk[a];
#pragma unroll 4
  for (int h = 0; h < 1024; ++h) acc += qs[h] * Wq[(size_t)h * 1024 + a];
  qb[(size_t)b * 1024 + a] = acc;
}

// ---------- GEMM1: align = tanh(seqb@WkT^T + query) -> bf16 ----------
__global__ __launch_bounds__(512, 2) void gemm1_kernel(
    const unsigned short* __restrict__ seqb, const unsigned short* __restrict__ WkT,
    const float* __restrict__ qb, unsigned short* __restrict__ alignb) {
  __shared__ unsigned short As0[BM * BK], Bs0[BN * BK], As1[BM * BK], Bs1[BN * BK];
  int m0, n0, nt;
  tile_coords(blockIdx.x, m0, n0, nt);
  int t = threadIdx.x, lane = t & 63, wave = t >> 6;
  int wr = wave >> 2, wc = wave & 3;
  f32x4 acc[8][4] = {};
  GEMM_PIPELINE(seqb, WkT)

  const float* qrow = qb + (size_t)(m0 >> 11) * 1024;  // 256-row tile stays in one batch
#pragma unroll
  for (int mi = 0; mi < 8; ++mi) {
    int row0 = m0 + wr * 128 + mi * 16 + ((lane >> 4) * 4);
#pragma unroll
    for (int ni = 0; ni < 4; ++ni) {
      int col = n0 + wc * 64 + ni * 16 + (lane & 15);
      float qv = qrow[col];
#pragma unroll
      for (int j = 0; j < 4; ++j) {
        float v = tanhf(acc[mi][ni][j] + qv);
        alignb[(size_t)(row0 + j) * 1024 + col] = f2bf(v);
      }
    }
  }
}

// ---------- GEMM2: scores_part[nt,row] = sum_col align*sigmoid(align@Wg+bg)*Ws ----------
__global__ __launch_bounds__(512, 2) void gemm2_kernel(
    const unsigned short* __restrict__ alignb, const unsigned short* __restrict__ WgT,
    const float* __restrict__ bg, const float* __restrict__ Ws,
    float* __restrict__ scores_part) {
  __shared__ unsigned short As0[BM * BK], Bs0[BN * BK], As1[BM * BK], Bs1[BN * BK];
  __shared__ float sred[BM * 4];
  int m0, n0, nt;
  tile_coords(blockIdx.x, m0, n0, nt);
  int t = threadIdx.x, lane = t & 63, wave = t >> 6;
  int wr = wave >> 2, wc = wave & 3;
  f32x4 acc[8][4] = {};
  GEMM_PIPELINE(alignb, WgT)

#pragma unroll
  for (int mi = 0; mi < 8; ++mi) {
#pragma unroll
    for (int j = 0; j < 4; ++j) {
      int rloc = wr * 128 + mi * 16 + ((lane >> 4) * 4) + j;
      int row = m0 + rloc;
      float p = 0.f;
#pragma unroll
      for (int ni = 0; ni < 4; ++ni) {
        int col = n0 + wc * 64 + ni * 16 + (lane & 15);
        float gp = acc[mi][ni][j] + bg[col];
        float gate = 1.f / (1.f + expf(-gp));
        float al = bf2f(alignb[(size_t)row * 1024 + col]);
        p += al * gate * Ws[col];
      }
      p += __shfl_xor(p, 1);
      p += __shfl_xor(p, 2);
      p += __shfl_xor(p, 4);
      p += __shfl_xor(p, 8);
      if ((lane & 15) == 0) sred[rloc * 4 + wc] = p;
    }
  }
  __syncthreads();
  if (t < 256)
    scores_part[(size_t)nt * 65536 + m0 + t] =
        sred[t * 4] + sred[t * 4 + 1] + sred[t * 4 + 2] + sred[t * 4 + 3];
}

// ---------- softmax over S=2048 per batch; writes weights output ----------
__global__ __launch_bounds__(256) void softmax_kernel(const float* __restrict__ sp,
                                                      float* __restrict__ wout) {
  __shared__ float red[256];
  int b = blockIdx.x, t = threadIdx.x;
  float sc[8];
  float lmax = -1e30f;
#pragma unroll
  for (int i = 0; i < 8; ++i) {
    int s = i * 256 + t;
    float v = 0.f;
#pragma unroll
    for (int n = 0; n < 4; ++n) v += sp[(size_t)n * 65536 + b * 2048 + s];
    sc[i] = v;
    lmax = fmaxf(lmax, v);
  }
  red[t] = lmax;
  __syncthreads();
  for (int off = 128; off > 0; off >>= 1) {
    if (t < off) red[t] = fmaxf(red[t], red[t + off]);
    __syncthreads();
  }
  float mx = red[0];
  __syncthreads();
  float lsum = 0.f;
#pragma unroll
  for (int i = 0; i < 8; ++i) {
    sc[i] = expf(sc[i] - mx);
    lsum += sc[i];
  }
  red[t] = lsum;
  __syncthreads();
  for (int off = 128; off > 0; off >>= 1) {
    if (t < off) red[t] += red[t + off];
    __syncthreads();
  }
  float inv = 1.f / red[0];
#pragma unroll
  for (int i = 0; i < 8; ++i) wout[(size_t)b * 2048 + i * 256 + t] = sc[i] * inv;
}

// ---------- context partials (bf16 seq read, 4 h per thread, 8 s-chunks) ----------
__global__ __launch_bounds__(256) void context_kernel(const unsigned short* __restrict__ seqb,
                                                      const float* __restrict__ wts,
                                                      float* __restrict__ ctx_part) {
  __shared__ float wsh[256];
  int b = blockIdx.x, t = threadIdx.x, s0 = blockIdx.z * 256;
  int h0 = t * 4;
  wsh[t] = wts[(size_t)b * 2048 + s0 + t];
  __syncthreads();
  float a0 = 0.f, a1 = 0.f, a2 = 0.f, a3 = 0.f;
  const unsigned short* p = seqb + ((size_t)b * 2048 + s0) * 1024 + h0;
#pragma unroll 4
  for (int s = 0; s < 256; ++s) {
    ushortx4 v = *(const ushortx4*)(p + (size_t)s * 1024);
    float w = wsh[s];
    a0 += w * bf2f(v[0]);
    a1 += w * bf2f(v[1]);
    a2 += w * bf2f(v[2]);
    a3 += w * bf2f(v[3]);
  }
  float* dst = ctx_part + (size_t)(blockIdx.z * 32 + b) * 1024 + h0;
  dst[0] = a0; dst[1] = a1; dst[2] = a2; dst[3] = a3;
}

// ---------- pre partials: pre_part[kc,b,h] = sum_{k in chunk} fin[k]*Wo[k,h] ----------
__global__ __launch_bounds__(256) void pre_kernel(const float* __restrict__ ctx_part,
                                                  const float* __restrict__ q,
                                                  const float* __restrict__ Wo,
                                                  float* __restrict__ pre_part) {
  __shared__ float fin[256];
  int b = blockIdx.x, k0 = blockIdx.y * 256, t = threadIdx.x;
  int k = k0 + t;
  float f;
  if (k < 1024) {
    f = 0.f;
#pragma unroll
    for (int sc = 0; sc < 8; ++sc) f += ctx_part[(size_t)(sc * 32 + b) * 1024 + k];
  } else {
    f = q[(size_t)b * 1024 + (k - 1024)];
  }
  fin[t] = f;
  __syncthreads();
  float a0 = 0.f, a1 = 0.f, a2 = 0.f, a3 = 0.f;
#pragma unroll 4
  for (int kk = 0; kk < 256; ++kk) {
    float fv = fin[kk];
    const float* wrow = Wo + (size_t)(k0 + kk) * 1024;
    a0 += fv * wrow[t];
    a1 += fv * wrow[t + 256];
    a2 += fv * wrow[t + 512];
    a3 += fv * wrow[t + 768];
  }
  float* dst = pre_part + (size_t)(blockIdx.y * 32 + b) * 1024;
  dst[t] = a0;
  dst[t + 256] = a1;
  dst[t + 512] = a2;
  dst[t + 768] = a3;
}

// ---------- final: residual + layernorm ----------
__global__ __launch_bounds__(256) void ln_kernel(const float* __restrict__ pre_part,
                                                 const float* __restrict__ q,
                                                 const float* __restrict__ bo,
                                                 const float* __restrict__ gamma,
                                                 const float* __restrict__ beta,
                                                 float* __restrict__ outF) {
  __shared__ float red[256];
  int b = blockIdx.x, t = threadIdx.x;
  float v[4];
  float lsum = 0.f;
#pragma unroll
  for (int i = 0; i < 4; ++i) {
    int h = i * 256 + t;
    float x = bo[h] + q[(size_t)b * 1024 + h];
#pragma unroll
    for (int kc = 0; kc < 8; ++kc) x += pre_part[(size_t)(kc * 32 + b) * 1024 + h];
    v[i] = x;
    lsum += x;
  }
  red[t] = lsum;
  __syncthreads();
  for (int off = 128; off > 0; off >>= 1) {
    if (t < off) red[t] += red[t + off];
    __syncthreads();
  }
  float mu = red[0] * (1.f / 1024.f);
  __syncthreads();
  float lv = 0.f;
#pragma unroll
  for (int i = 0; i < 4; ++i) {
    float d = v[i] - mu;
    lv += d * d;
  }
  red[t] = lv;
  __syncthreads();
  for (int off = 128; off > 0; off >>= 1) {
    if (t < off) red[t] += red[t + off];
    __syncthreads();
  }
  float var = red[0] * (1.f / 1024.f);
  float rs = rsqrtf(var + 1e-5f);
#pragma unroll
  for (int i = 0; i < 4; ++i) {
    int h = i * 256 + t;
    outF[(size_t)b * 1024 + h] = (v[i] - mu) * rs * gamma[h] + beta[h];
  }
}

// ---------- host ----------
extern "C" void kernel_launch(void* const* d_in, const int* in_sizes, int n_in,
                              void* d_out, int out_size, void* d_ws, size_t ws_size,
                              hipStream_t stream) {
  const float* seq = (const float*)d_in[0];
  const float* q = (const float*)d_in[1];
  const float* Wk = (const float*)d_in[2];
  const float* bk = (const float*)d_in[3];
  const float* Wq = (const float*)d_in[4];
  const float* bq = (const float*)d_in[5];
  const float* Wg = (const float*)d_in[6];
  const float* bg = (const float*)d_in[7];
  const float* Ws = (const float*)d_in[8];
  // d_in[9] = bs: softmax is shift-invariant, cancels everywhere it appears
  const float* Wo = (const float*)d_in[10];
  const float* bo = (const float*)d_in[11];
  const float* gamma = (const float*)d_in[12];
  const float* beta = (const float*)d_in[13];

  float* outF = (float*)d_out;         // fused [32,1024]
  float* outW = outF + 32 * 1024;      // weights [32,2048]

  char* ws = (char*)d_ws;
  unsigned short* alignb = (unsigned short*)ws;  ws += (size_t)134217728;  // [65536,1024] bf16
  unsigned short* seqb = (unsigned short*)ws;    ws += (size_t)134217728;  // [65536,1024] bf16
  unsigned short* WkT = (unsigned short*)ws;     ws += 2097152;            // [1024,1024] bf16
  unsigned short* WgT = (unsigned short*)ws;     ws += 2097152;
  float* qb = (float*)ws;                        ws += 131072;             // [32,1024]
  float* scores_part = (float*)ws;               ws += 1048576;            // [4,65536]
  float* ctx_part = (float*)ws;                  ws += 1048576;            // [8,32,1024]
  float* pre_part = (float*)ws;                  ws += 1048576;            // [8,32,1024]
  if (ws_size < (size_t)(ws - (char*)d_ws)) return;  // insufficient scratch

  convert_kernel<<<2048, 256, 0, stream>>>(seq, seqb);
  transpose_kernel<<<512, 256, 0, stream>>>(Wk, Wg, WkT, WgT);
  query_kernel<<<dim3(32, 4), 256, 0, stream>>>(q, Wq, bq, bk, qb);
  gemm1_kernel<<<1024, 512, 0, stream>>>(seqb, WkT, qb, alignb);
  gemm2_kernel<<<1024, 512, 0, stream>>>(alignb, WgT, bg, Ws, scores_part);
  softmax_kernel<<<32, 256, 0, stream>>>(scores_part, outW);
  context_kernel<<<dim3(32, 1, 8), 256, 0, stream>>>(seqb, outW, ctx_part);
  pre_kernel<<<dim3(32, 8), 256, 0, stream>>>(ctx_part, q, Wo, pre_part);
  ln_kernel<<<32, 256, 0, stream>>>(pre_part, q, bo, gamma, beta, outF);
}

// Round 6
// 552.381 us; speedup vs baseline: 1.4207x; 1.1899x over previous
//
#include <hip/hip_runtime.h>

typedef __attribute__((ext_vector_type(8))) short bf16x8;
typedef __attribute__((ext_vector_type(8))) unsigned short ushort8;
typedef __attribute__((ext_vector_type(4))) unsigned short ushortx4;
typedef __attribute__((ext_vector_type(4))) float f32x4;

#define BM 256
#define BN 256
#define BK 64

// ---------- helpers ----------
__device__ __forceinline__ unsigned short f2bf(float f) {
  union { float f; unsigned u; } c; c.f = f;
  return (unsigned short)((c.u + 0x7fffu + ((c.u >> 16) & 1u)) >> 16);  // RNE
}
__device__ __forceinline__ float bf2f(unsigned short u) {
  union { unsigned u; float f; } c; c.u = ((unsigned)u) << 16;
  return c.f;
}
__device__ __forceinline__ void gload16(const void* g, void* lds) {
  __builtin_amdgcn_global_load_lds(
      (const __attribute__((address_space(1))) unsigned int*)g,
      (__attribute__((address_space(3))) unsigned int*)lds, 16, 0, 0);
}
__device__ __forceinline__ void bar() {
  asm volatile("" ::: "memory");
  __builtin_amdgcn_s_barrier();
  asm volatile("" ::: "memory");
}
template <int N> __device__ __forceinline__ void vwait() {
  if constexpr (N < 0) {
  } else if constexpr (N == 6) asm volatile("s_waitcnt vmcnt(6)" ::: "memory");
  else if constexpr (N == 0) asm volatile("s_waitcnt vmcnt(0)" ::: "memory");
}

__device__ __forceinline__ void mfma_q(const bf16x8 (&av)[2][4], const bf16x8 (&bv)[2][2],
                                       int qm, int qn, f32x4 (&acc)[8][4]) {
  __builtin_amdgcn_s_setprio(1);
#pragma unroll
  for (int kk = 0; kk < 2; ++kk)
#pragma unroll
    for (int i = 0; i < 4; ++i)
#pragma unroll
      for (int j = 0; j < 2; ++j)
        acc[qm * 4 + i][qn * 2 + j] = __builtin_amdgcn_mfma_f32_16x16x32_bf16(
            av[kk][i], bv[kk][j], acc[qm * 4 + i][qn * 2 + j], 0, 0, 0);
  __builtin_amdgcn_s_setprio(0);
}

// K-tile = 4 phases, quadrants (qm,qn) = (0,0),(0,1),(1,1),(1,0).
// Per phase: {ds_reads for THIS phase (base + imm offsets only); stage issue;
// MFMA (compiler inserts fine lgkmcnt); bar}. One counted vmcnt(6) per K-tile
// at phase-4 end: retires exactly next tile's 4 half-tiles, leaves 3 half-tile
// slots (6 loads) in flight -- m201's steady state.
// LDS byte offsets: row stride 128 B; half (qm/qn=1) = +128 rows = +16384 B.
template <bool S1, bool S234, int WEND>
__device__ __forceinline__ void ktile(
    const char* rA0, const char* rA1,       // cur-A read bases (kk=0/1 slots)
    const char* rB0, const char* rB1,       // cur-B read bases
    char* dNxtA, char* dCurA, char* dCurB,  // stage dest bases (buf + t*16)
    const unsigned short* pA0, const unsigned short* pA1,
    const unsigned short* pB0, const unsigned short* pB1,
    int kA1, int k2, f32x4 (&acc)[8][4]) {
  bf16x8 av[2][4], a2[2][4], bv0[2][2], bv1[2][2];
  // ---- phase 1: q(0,0); read A-h0 + B-h0; stage A(t+1)h1 -> nxtA.h1
#pragma unroll
  for (int kk = 0; kk < 2; ++kk) {
    const char* ra = kk ? rA1 : rA0;
    const char* rb = kk ? rB1 : rB0;
#pragma unroll
    for (int i = 0; i < 4; ++i) av[kk][i] = *(const bf16x8*)(ra + i * 2048);
#pragma unroll
    for (int j = 0; j < 2; ++j) bv0[kk][j] = *(const bf16x8*)(rb + j * 2048);
  }
  if (S1) {
    gload16(pA0 + 65536 + kA1, dNxtA + 16384);
    gload16(pA1 + 65536 + kA1, dNxtA + 16384 + 8192);
  }
  mfma_q(av, bv0, 0, 0, acc);
  bar();
  // ---- phase 2: q(0,1); read B-h1 (+16384 B); stage A(t+2)h0 -> curA.h0
#pragma unroll
  for (int kk = 0; kk < 2; ++kk) {
    const char* rb = kk ? rB1 : rB0;
#pragma unroll
    for (int j = 0; j < 2; ++j) bv1[kk][j] = *(const bf16x8*)(rb + 16384 + j * 2048);
  }
  if (S234) {
    gload16(pA0 + k2, dCurA);
    gload16(pA1 + k2, dCurA + 8192);
  }
  mfma_q(av, bv1, 0, 1, acc);
  bar();
  // ---- phase 3: q(1,1); read A-h1 (+16384 B); stage B(t+2)h0 -> curB.h0
#pragma unroll
  for (int kk = 0; kk < 2; ++kk) {
    const char* ra = kk ? rA1 : rA0;
#pragma unroll
    for (int i = 0; i < 4; ++i) a2[kk][i] = *(const bf16x8*)(ra + 16384 + i * 2048);
  }
  if (S234) {
    gload16(pB0 + k2, dCurB);
    gload16(pB1 + k2, dCurB + 8192);
  }
  mfma_q(a2, bv1, 1, 1, acc);
  bar();
  // ---- phase 4: q(1,0); no reads; stage B(t+2)h1 -> curB.h1
  if (S234) {
    gload16(pB0 + 32768 + k2, dCurB + 16384);
    gload16(pB1 + 32768 + k2, dCurB + 16384 + 8192);
  }
  mfma_q(a2, bv0, 1, 0, acc);
  vwait<WEND>();
  bar();
}

// Shared setup + pipeline for both GEMMs. LDS layout (verified r3/r4):
// A rows: la = qm*128 + wr*64 + i*16 + (lane&15) holds tile row wr*128+qm*64+i*16+(lane&15)
// byte(l,slot s) = l*128 + (s^(l&7))*16; staged linear-dest with inverse-swz source.
#define GEMM_SETUP_AND_PIPELINE(Ag, Bg)                                                    \
  int t = threadIdx.x, lane = t & 63, wave = t >> 6;                                       \
  int wr = wave >> 2, wc = wave & 3;                                                       \
  int sl0 = ((lane >> 4) ^ (lane & 7)) * 16;                                               \
  int sl1 = (((lane >> 4) + 4) ^ (lane & 7)) * 16;                                         \
  int aLane = (wr * 64 + (lane & 15)) * 128;                                               \
  int bLane = (wc * 32 + (lane & 15)) * 128;                                               \
  const char* rA0k0 = (const char*)As0 + aLane + sl0;                                      \
  const char* rA0k1 = (const char*)As0 + aLane + sl1;                                      \
  const char* rA1k0 = (const char*)As1 + aLane + sl0;                                      \
  const char* rA1k1 = (const char*)As1 + aLane + sl1;                                      \
  const char* rB0k0 = (const char*)Bs0 + bLane + sl0;                                      \
  const char* rB0k1 = (const char*)Bs0 + bLane + sl1;                                      \
  const char* rB1k0 = (const char*)Bs1 + bLane + sl0;                                      \
  const char* rB1k1 = (const char*)Bs1 + bLane + sl1;                                      \
  char* dA0 = (char*)As0 + t * 16;                                                         \
  char* dA1 = (char*)As1 + t * 16;                                                         \
  char* dB0 = (char*)Bs0 + t * 16;                                                         \
  char* dB1 = (char*)Bs1 + t * 16;                                                         \
  int l3 = t >> 3;                                                                         \
  int sgE = ((t & 7) ^ (l3 & 7)) * 8;                                                      \
  const unsigned short* pA0 = Ag + (size_t)(m0 + l3) * 1024 + sgE;                         \
  const unsigned short* pA1 = pA0 + (size_t)128 * 1024;                                    \
  int nB0 = ((l3 >> 5) << 6) + (l3 & 31);                                                  \
  const unsigned short* pB0 = Bg + (size_t)(n0 + nB0) * 1024 + sgE;                        \
  const unsigned short* pB1 = pB0 + (size_t)128 * 1024;                                    \
  f32x4 acc[8][4] = {};                                                                    \
  /* prologue: 7 half-tile slots: A0h0,B0h0,B0h1,A0h1,A1h0,B1h0,B1h1 */                    \
  gload16(pA0, dA0); gload16(pA1, dA0 + 8192);                                             \
  gload16(pB0, dB0); gload16(pB1, dB0 + 8192);                                             \
  gload16(pB0 + 32768, dB0 + 16384); gload16(pB1 + 32768, dB0 + 16384 + 8192);             \
  gload16(pA0 + 65536, dA0 + 16384); gload16(pA1 + 65536, dA0 + 16384 + 8192);             \
  gload16(pA0 + 64, dA1); gload16(pA1 + 64, dA1 + 8192);                                   \
  gload16(pB0 + 64, dB1); gload16(pB1 + 64, dB1 + 8192);                                   \
  gload16(pB0 + 32768 + 64, dB1 + 16384); gload16(pB1 + 32768 + 64, dB1 + 16384 + 8192);   \
  vwait<6>();                                                                              \
  bar();                                                                                   \
  _Pragma("unroll 1") for (int kt = 0; kt < 14; kt += 2) {                                 \
    ktile<true, true, 6>(rA0k0, rA0k1, rB0k0, rB0k1, dA1, dA0, dB0, pA0, pA1, pB0, pB1,    \
                         (kt + 1) * 64, (kt + 2) * 64, acc);                               \
    ktile<true, true, 6>(rA1k0, rA1k1, rB1k0, rB1k1, dA0, dA1, dB1, pA0, pA1, pB0, pB1,    \
                         (kt + 2) * 64, (kt + 3) * 64, acc);                               \
  }                                                                                        \
  ktile<true, false, 0>(rA0k0, rA0k1, rB0k0, rB0k1, dA1, dA0, dB0, pA0, pA1, pB0, pB1,     \
                        15 * 64, 0, acc);                                                  \
  ktile<false, false, -1>(rA1k0, rA1k1, rB1k0, rB1k1, dA0, dA1, dB1, pA0, pA1, pB0, pB1,   \
                          0, 0, acc);

__device__ __forceinline__ void tile_coords(int bid, int& m0, int& n0, int& nt) {
  // 1024 blocks, 8 XCDs, bijective; nt fastest within an XCD for A-panel L2 reuse
  int lin = (bid & 7) * 128 + (bid >> 3);
  int mt = lin >> 2;
  nt = lin & 3;
  m0 = mt * BM;
  n0 = nt * BN;
}

// ---------- prep: convert (2048 blocks) + transpose (512) + query partials (32) ----------
__global__ __launch_bounds__(256) void prep_kernel(
    const float* __restrict__ seq, unsigned short* __restrict__ seqb,
    const float* __restrict__ Wk, const float* __restrict__ Wg,
    unsigned short* __restrict__ WkT, unsigned short* __restrict__ WgT,
    const float* __restrict__ q, const float* __restrict__ Wq,
    float* __restrict__ qp) {
  __shared__ float smem[4160];
  int bid = blockIdx.x, t = threadIdx.x;
  if (bid < 2048) {
    size_t i = ((size_t)bid * 256 + t) * 8;
    const size_t stride = (size_t)2048 * 256 * 8;
    for (; i < (size_t)67108864; i += stride) {
      f32x4 v0 = *(const f32x4*)(seq + i);
      f32x4 v1 = *(const f32x4*)(seq + i + 4);
      ushort8 o;
#pragma unroll
      for (int k = 0; k < 4; ++k) { o[k] = f2bf(v0[k]); o[k + 4] = f2bf(v1[k]); }
      *(ushort8*)(seqb + i) = o;
    }
  } else if (bid < 2560) {
    int b2 = bid - 2048;
    int mat = b2 >> 8;
    int tid = b2 & 255;
    int tr = tid >> 4, tc = tid & 15;
    const float* src = mat ? Wg : Wk;
    unsigned short* dst = mat ? WgT : WkT;
    int r0 = tr * 64, c0 = tc * 64;
    int lr = t >> 6, lc = t & 63;
#pragma unroll
    for (int i = 0; i < 16; ++i) {
      int r = i * 4 + lr;
      smem[r * 65 + lc] = src[(size_t)(r0 + r) * 1024 + c0 + lc];
    }
    __syncthreads();
#pragma unroll
    for (int i = 0; i < 16; ++i) {
      int r = i * 4 + lr;
      dst[(size_t)(c0 + r) * 1024 + r0 + lc] = f2bf(smem[lc * 65 + r]);
    }
  } else {
    // query partials: qp[hc][b][a] = sum_{h in chunk} q[b][h]*Wq[h][a]
    int b3 = bid - 2560;           // 32 blocks
    int ac = b3 & 3, hc = b3 >> 2; // 4 a-chunks x 8 h-chunks
    int h0 = hc * 128;
    for (int i = t; i < 4096; i += 256) {
      int b = i >> 7, hh = i & 127;
      smem[b * 128 + hh] = q[(size_t)b * 1024 + h0 + hh];
    }
    __syncthreads();
    int a = ac * 256 + t;
    float acc[32] = {};
    for (int hh = 0; hh < 128; hh += 4) {
      float w0 = Wq[(size_t)(h0 + hh) * 1024 + a];
      float w1 = Wq[(size_t)(h0 + hh + 1) * 1024 + a];
      float w2 = Wq[(size_t)(h0 + hh + 2) * 1024 + a];
      float w3 = Wq[(size_t)(h0 + hh + 3) * 1024 + a];
#pragma unroll
      for (int b = 0; b < 32; ++b) {
        f32x4 qv = *(const f32x4*)&smem[b * 128 + hh];
        acc[b] += qv[0] * w0 + qv[1] * w1 + qv[2] * w2 + qv[3] * w3;
      }
    }
#pragma unroll
    for (int b = 0; b < 32; ++b) qp[((size_t)(hc * 32 + b)) * 1024 + a] = acc[b];
  }
}

// ---------- GEMM1: align = tanh(seqb@WkT^T + query) -> bf16 ----------
__global__ __launch_bounds__(512, 2) void gemm1_kernel(
    const unsigned short* __restrict__ seqb, const unsigned short* __restrict__ WkT,
    const float* __restrict__ qp, const float* __restrict__ bq,
    const float* __restrict__ bk, unsigned short* __restrict__ alignb) {
  __shared__ unsigned short As0[BM * BK], Bs0[BN * BK], As1[BM * BK], Bs1[BN * BK];
  int m0, n0, nt;
  tile_coords(blockIdx.x, m0, n0, nt);
  GEMM_SETUP_AND_PIPELINE(seqb, WkT)

  // epilogue: fold query reduce (8 partials + bq + bk), tanh, store bf16
  int bidx = m0 >> 11;  // 256-row tile stays in one batch (2048 % 256 == 0)
  float qv[4];
#pragma unroll
  for (int ni = 0; ni < 4; ++ni) {
    int col = n0 + wc * 64 + ni * 16 + (lane & 15);
    float s = bq[col] + bk[col];
#pragma unroll
    for (int hc = 0; hc < 8; ++hc) s += qp[((size_t)(hc * 32 + bidx)) * 1024 + col];
    qv[ni] = s;
  }
#pragma unroll
  for (int mi = 0; mi < 8; ++mi) {
    int row0 = m0 + wr * 128 + mi * 16 + ((lane >> 4) * 4);
#pragma unroll
    for (int ni = 0; ni < 4; ++ni) {
      int col = n0 + wc * 64 + ni * 16 + (lane & 15);
#pragma unroll
      for (int j = 0; j < 4; ++j) {
        float v = tanhf(acc[mi][ni][j] + qv[ni]);
        alignb[(size_t)(row0 + j) * 1024 + col] = f2bf(v);
      }
    }
  }
}

// ---------- GEMM2: scores_part[nt,row] = sum_col align*sigmoid(align@Wg+bg)*Ws ----------
__global__ __launch_bounds__(512, 2) void gemm2_kernel(
    const unsigned short* __restrict__ alignb, const unsigned short* __restrict__ WgT,
    const float* __restrict__ bg, const float* __restrict__ Ws,
    float* __restrict__ scores_part) {
  __shared__ unsigned short As0[BM * BK], Bs0[BN * BK], As1[BM * BK], Bs1[BN * BK];
  __shared__ float sred[BM * 4];
  int m0, n0, nt;
  tile_coords(blockIdx.x, m0, n0, nt);
  GEMM_SETUP_AND_PIPELINE(alignb, WgT)

#pragma unroll
  for (int mi = 0; mi < 8; ++mi) {
#pragma unroll
    for (int j = 0; j < 4; ++j) {
      int rloc = wr * 128 + mi * 16 + ((lane >> 4) * 4) + j;
      int row = m0 + rloc;
      float p = 0.f;
#pragma unroll
      for (int ni = 0; ni < 4; ++ni) {
        int col = n0 + wc * 64 + ni * 16 + (lane & 15);
        float gp = acc[mi][ni][j] + bg[col];
        float gate = 1.f / (1.f + expf(-gp));
        float al = bf2f(alignb[(size_t)row * 1024 + col]);
        p += al * gate * Ws[col];
      }
      p += __shfl_xor(p, 1);
      p += __shfl_xor(p, 2);
      p += __shfl_xor(p, 4);
      p += __shfl_xor(p, 8);
      if ((lane & 15) == 0) sred[rloc * 4 + wc] = p;
    }
  }
  __syncthreads();
  if (t < 256)
    scores_part[(size_t)nt * 65536 + m0 + t] =
        sred[t * 4] + sred[t * 4 + 1] + sred[t * 4 + 2] + sred[t * 4 + 3];
}

// ---------- softmax over S=2048 per batch; writes weights output ----------
__global__ __launch_bounds__(256) void softmax_kernel(const float* __restrict__ sp,
                                                      float* __restrict__ wout) {
  __shared__ float red[256];
  int b = blockIdx.x, t = threadIdx.x;
  float sc[8];
  float lmax = -1e30f;
#pragma unroll
  for (int i = 0; i < 8; ++i) {
    int s = i * 256 + t;
    float v = 0.f;
#pragma unroll
    for (int n = 0; n < 4; ++n) v += sp[(size_t)n * 65536 + b * 2048 + s];
    sc[i] = v;
    lmax = fmaxf(lmax, v);
  }
  red[t] = lmax;
  __syncthreads();
  for (int off = 128; off > 0; off >>= 1) {
    if (t < off) red[t] = fmaxf(red[t], red[t + off]);
    __syncthreads();
  }
  float mx = red[0];
  __syncthreads();
  float lsum = 0.f;
#pragma unroll
  for (int i = 0; i < 8; ++i) {
    sc[i] = expf(sc[i] - mx);
    lsum += sc[i];
  }
  red[t] = lsum;
  __syncthreads();
  for (int off = 128; off > 0; off >>= 1) {
    if (t < off) red[t] += red[t + off];
    __syncthreads();
  }
  float inv = 1.f / red[0];
#pragma unroll
  for (int i = 0; i < 8; ++i) wout[(size_t)b * 2048 + i * 256 + t] = sc[i] * inv;
}

// ---------- context partials (bf16 seq read, 4 h per thread, 8 s-chunks) ----------
__global__ __launch_bounds__(256) void context_kernel(const unsigned short* __restrict__ seqb,
                                                      const float* __restrict__ wts,
                                                      float* __restrict__ ctx_part) {
  __shared__ float wsh[256];
  int b = blockIdx.x, t = threadIdx.x, s0 = blockIdx.z * 256;
  int h0 = t * 4;
  wsh[t] = wts[(size_t)b * 2048 + s0 + t];
  __syncthreads();
  float a0 = 0.f, a1 = 0.f, a2 = 0.f, a3 = 0.f;
  const unsigned short* p = seqb + ((size_t)b * 2048 + s0) * 1024 + h0;
#pragma unroll 4
  for (int s = 0; s < 256; ++s) {
    ushortx4 v = *(const ushortx4*)(p + (size_t)s * 1024);
    float w = wsh[s];
    a0 += w * bf2f(v[0]);
    a1 += w * bf2f(v[1]);
    a2 += w * bf2f(v[2]);
    a3 += w * bf2f(v[3]);
  }
  float* dst = ctx_part + (size_t)(blockIdx.z * 32 + b) * 1024 + h0;
  dst[0] = a0; dst[1] = a1; dst[2] = a2; dst[3] = a3;
}

// ---------- pre partials: Wo read ONCE. grid (16 k-chunks of 128, 4 h-chunks) ----------
__global__ __launch_bounds__(256) void pre_kernel(const float* __restrict__ ctx_part,
                                                  const float* __restrict__ q,
                                                  const float* __restrict__ Wo,
                                                  float* __restrict__ pre_part) {
  __shared__ float fin[32 * 128];
  int kc = blockIdx.x, hc = blockIdx.y, t = threadIdx.x;
  int k0 = kc * 128, h0 = hc * 256;
  for (int i = t; i < 4096; i += 256) {
    int b = i >> 7, kk = i & 127, k = k0 + kk;
    float f;
    if (k < 1024) {
      f = 0.f;
#pragma unroll
      for (int s = 0; s < 8; ++s) f += ctx_part[((size_t)(s * 32 + b)) * 1024 + k];
    } else {
      f = q[(size_t)b * 1024 + (k - 1024)];
    }
    fin[b * 128 + kk] = f;
  }
  __syncthreads();
  int h = h0 + t;
  float acc[32] = {};
  for (int kk = 0; kk < 128; kk += 4) {
    float w0 = Wo[(size_t)(k0 + kk) * 1024 + h];
    float w1 = Wo[(size_t)(k0 + kk + 1) * 1024 + h];
    float w2 = Wo[(size_t)(k0 + kk + 2) * 1024 + h];
    float w3 = Wo[(size_t)(k0 + kk + 3) * 1024 + h];
#pragma unroll
    for (int b = 0; b < 32; ++b) {
      f32x4 fv = *(const f32x4*)&fin[b * 128 + kk];
      acc[b] += fv[0] * w0 + fv[1] * w1 + fv[2] * w2 + fv[3] * w3;
    }
  }
#pragma unroll
  for (int b = 0; b < 32; ++b) pre_part[((size_t)(kc * 32 + b)) * 1024 + h] = acc[b];
}

// ---------- final: residual + layernorm ----------
__global__ __launch_bounds__(256) void ln_kernel(const float* __restrict__ pre_part,
                                                 const float* __restrict__ q,
                                                 const float* __restrict__ bo,
                                                 const float* __restrict__ gamma,
                                                 const float* __restrict__ beta,
                                                 float* __restrict__ outF) {
  __shared__ float red[256];
  int b = blockIdx.x, t = threadIdx.x;
  float v[4];
  float lsum = 0.f;
#pragma unroll
  for (int i = 0; i < 4; ++i) {
    int h = i * 256 + t;
    float x = bo[h] + q[(size_t)b * 1024 + h];
#pragma unroll
    for (int kc = 0; kc < 16; ++kc) x += pre_part[((size_t)(kc * 32 + b)) * 1024 + h];
    v[i] = x;
    lsum += x;
  }
  red[t] = lsum;
  __syncthreads();
  for (int off = 128; off > 0; off >>= 1) {
    if (t < off) red[t] += red[t + off];
    __syncthreads();
  }
  float mu = red[0] * (1.f / 1024.f);
  __syncthreads();
  float lv = 0.f;
#pragma unroll
  for (int i = 0; i < 4; ++i) {
    float d = v[i] - mu;
    lv += d * d;
  }
  red[t] = lv;
  __syncthreads();
  for (int off = 128; off > 0; off >>= 1) {
    if (t < off) red[t] += red[t + off];
    __syncthreads();
  }
  float var = red[0] * (1.f / 1024.f);
  float rs = rsqrtf(var + 1e-5f);
#pragma unroll
  for (int i = 0; i < 4; ++i) {
    int h = i * 256 + t;
    outF[(size_t)b * 1024 + h] = (v[i] - mu) * rs * gamma[h] + beta[h];
  }
}

// ---------- host ----------
extern "C" void kernel_launch(void* const* d_in, const int* in_sizes, int n_in,
                              void* d_out, int out_size, void* d_ws, size_t ws_size,
                              hipStream_t stream) {
  const float* seq = (const float*)d_in[0];
  const float* q = (const float*)d_in[1];
  const float* Wk = (const float*)d_in[2];
  const float* bk = (const float*)d_in[3];
  const float* Wq = (const float*)d_in[4];
  const float* bq = (const float*)d_in[5];
  const float* Wg = (const float*)d_in[6];
  const float* bg = (const float*)d_in[7];
  const float* Ws = (const float*)d_in[8];
  // d_in[9] = bs: softmax is shift-invariant, cancels everywhere it appears
  const float* Wo = (const float*)d_in[10];
  const float* bo = (const float*)d_in[11];
  const float* gamma = (const float*)d_in[12];
  const float* beta = (const float*)d_in[13];

  float* outF = (float*)d_out;         // fused [32,1024]
  float* outW = outF + 32 * 1024;      // weights [32,2048]

  char* ws = (char*)d_ws;
  unsigned short* alignb = (unsigned short*)ws;  ws += (size_t)134217728;  // [65536,1024] bf16
  unsigned short* seqb = (unsigned short*)ws;    ws += (size_t)134217728;  // [65536,1024] bf16
  unsigned short* WkT = (unsigned short*)ws;     ws += 2097152;            // [1024,1024] bf16
  unsigned short* WgT = (unsigned short*)ws;     ws += 2097152;
  float* qp = (float*)ws;                        ws += 1048576;            // [8,32,1024]
  float* scores_part = (float*)ws;               ws += 1048576;            // [4,65536]
  float* ctx_part = (float*)ws;                  ws += 1048576;            // [8,32,1024]
  float* pre_part = (float*)ws;                  ws += 2097152;            // [16,32,1024]
  if (ws_size < (size_t)(ws - (char*)d_ws)) return;  // insufficient scratch

  prep_kernel<<<2592, 256, 0, stream>>>(seq, seqb, Wk, Wg, WkT, WgT, q, Wq, qp);
  gemm1_kernel<<<1024, 512, 0, stream>>>(seqb, WkT, qp, bq, bk, alignb);
  gemm2_kernel<<<1024, 512, 0, stream>>>(alignb, WgT, bg, Ws, scores_part);
  softmax_kernel<<<32, 256, 0, stream>>>(scores_part, outW);
  context_kernel<<<dim3(32, 1, 8), 256, 0, stream>>>(seqb, outW, ctx_part);
  pre_kernel<<<dim3(16, 4), 256, 0, stream>>>(ctx_part, q, Wo, pre_part);
  ln_kernel<<<32, 256, 0, stream>>>(pre_part, q, bo, gamma, beta, outF);
}

// Round 7
// 501.756 us; speedup vs baseline: 1.5641x; 1.1009x over previous
//
#include <hip/hip_runtime.h>

typedef __attribute__((ext_vector_type(8))) short bf16x8;
typedef __attribute__((ext_vector_type(8))) unsigned short ushort8;
typedef __attribute__((ext_vector_type(4))) unsigned short ushortx4;
typedef __attribute__((ext_vector_type(4))) float f32x4;

#define BM 256
#define BN 256
#define BK 64

// ---------- helpers ----------
__device__ __forceinline__ unsigned short f2bf(float f) {
  union { float f; unsigned u; } c; c.f = f;
  return (unsigned short)((c.u + 0x7fffu + ((c.u >> 16) & 1u)) >> 16);  // RNE
}
__device__ __forceinline__ float bf2f(unsigned short u) {
  union { unsigned u; float f; } c; c.u = ((unsigned)u) << 16;
  return c.f;
}
__device__ __forceinline__ float fast_tanh(float x) {
  float e = __expf(2.f * x);                       // inf for large x -> rcp->0 -> 1
  return 1.f - 2.f * __builtin_amdgcn_rcpf(e + 1.f);
}
__device__ __forceinline__ float fast_sigmoid(float x) {
  return __builtin_amdgcn_rcpf(1.f + __expf(-x));
}
__device__ __forceinline__ void gload16(const void* g, void* lds) {
  __builtin_amdgcn_global_load_lds(
      (const __attribute__((address_space(1))) unsigned int*)g,
      (__attribute__((address_space(3))) unsigned int*)lds, 16, 0, 0);
}
__device__ __forceinline__ void bar() {
  asm volatile("" ::: "memory");
  __builtin_amdgcn_s_barrier();
  asm volatile("" ::: "memory");
}
// rule #18: explicit lgkmcnt wait + sched_barrier so MFMA can't hoist above it
__device__ __forceinline__ void lgkm0_fence() {
  asm volatile("s_waitcnt lgkmcnt(0)" ::: "memory");
  __builtin_amdgcn_sched_barrier(0);
}
template <int N> __device__ __forceinline__ void vwait() {
  if constexpr (N < 0) {
  } else if constexpr (N == 6) asm volatile("s_waitcnt vmcnt(6)" ::: "memory");
  else if constexpr (N == 0) asm volatile("s_waitcnt vmcnt(0)" ::: "memory");
}

__device__ __forceinline__ void mfma_q(const bf16x8 (&av)[2][4], const bf16x8 (&bv)[2][2],
                                       int qm, int qn, f32x4 (&acc)[8][4]) {
  __builtin_amdgcn_s_setprio(1);
#pragma unroll
  for (int kk = 0; kk < 2; ++kk)
#pragma unroll
    for (int i = 0; i < 4; ++i)
#pragma unroll
      for (int j = 0; j < 2; ++j)
        acc[qm * 4 + i][qn * 2 + j] = __builtin_amdgcn_mfma_f32_16x16x32_bf16(
            av[kk][i], bv[kk][j], acc[qm * 4 + i][qn * 2 + j], 0, 0, 0);
  __builtin_amdgcn_s_setprio(0);
}

// K-tile = 4 phases (m201 template): each phase = {ds_reads; stage issue} BAR
// {lgkmcnt(0); sched_barrier; setprio; 16 MFMA; setprio} BAR.
// Quadrants (qm,qn) = (0,0),(0,1),(1,1),(1,0); reads: ph1 A-h0+B-h0, ph2 B-h1,
// ph3 A-h1, ph4 none. Rolling stages: ph1 A(t+1)h1->nxtA, ph2 A(t+2)h0->curA,
// ph3 B(t+2)h0->curB, ph4 B(t+2)h1->curB. Single vmcnt(6) at ph4 end (ledger
// verified r4/r6: retires next tile's 4 half-tiles, leaves 3 slots in flight).
// LDS byte offsets: row stride 128 B; half (qm/qn=1) = +16384 B.
template <bool S1, bool S234, int WEND>
__device__ __forceinline__ void ktile(
    const char* rA0, const char* rA1,       // cur-A read bases (kk=0/1 slots)
    const char* rB0, const char* rB1,       // cur-B read bases
    char* dNxtA, char* dCurA, char* dCurB,  // stage dest bases (buf + t*16)
    const unsigned short* pA0, const unsigned short* pA1,
    const unsigned short* pB0, const unsigned short* pB1,
    int kA1, int k2, f32x4 (&acc)[8][4]) {
  bf16x8 av[2][4], a2[2][4], bv0[2][2], bv1[2][2];
  // ---- phase 1: read A-h0 + B-h0; stage A(t+1)h1 -> nxtA.h1; MFMA q(0,0)
#pragma unroll
  for (int kk = 0; kk < 2; ++kk) {
    const char* ra = kk ? rA1 : rA0;
    const char* rb = kk ? rB1 : rB0;
#pragma unroll
    for (int i = 0; i < 4; ++i) av[kk][i] = *(const bf16x8*)(ra + i * 2048);
#pragma unroll
    for (int j = 0; j < 2; ++j) bv0[kk][j] = *(const bf16x8*)(rb + j * 2048);
  }
  if (S1) {
    gload16(pA0 + 65536 + kA1, dNxtA + 16384);
    gload16(pA1 + 65536 + kA1, dNxtA + 16384 + 8192);
  }
  bar();
  lgkm0_fence();
  mfma_q(av, bv0, 0, 0, acc);
  bar();
  // ---- phase 2: read B-h1 (+16384); stage A(t+2)h0 -> curA.h0; MFMA q(0,1)
#pragma unroll
  for (int kk = 0; kk < 2; ++kk) {
    const char* rb = kk ? rB1 : rB0;
#pragma unroll
    for (int j = 0; j < 2; ++j) bv1[kk][j] = *(const bf16x8*)(rb + 16384 + j * 2048);
  }
  if (S234) {
    gload16(pA0 + k2, dCurA);
    gload16(pA1 + k2, dCurA + 8192);
  }
  bar();
  lgkm0_fence();
  mfma_q(av, bv1, 0, 1, acc);
  bar();
  // ---- phase 3: read A-h1 (+16384); stage B(t+2)h0 -> curB.h0; MFMA q(1,1)
#pragma unroll
  for (int kk = 0; kk < 2; ++kk) {
    const char* ra = kk ? rA1 : rA0;
#pragma unroll
    for (int i = 0; i < 4; ++i) a2[kk][i] = *(const bf16x8*)(ra + 16384 + i * 2048);
  }
  if (S234) {
    gload16(pB0 + k2, dCurB);
    gload16(pB1 + k2, dCurB + 8192);
  }
  bar();
  lgkm0_fence();
  mfma_q(a2, bv1, 1, 1, acc);
  bar();
  // ---- phase 4: no reads; stage B(t+2)h1 -> curB.h1; MFMA q(1,0); vmcnt
  if (S234) {
    gload16(pB0 + 32768 + k2, dCurB + 16384);
    gload16(pB1 + 32768 + k2, dCurB + 16384 + 8192);
  }
  bar();
  mfma_q(a2, bv0, 1, 0, acc);
  vwait<WEND>();
  bar();
}

// Shared setup + pipeline for both GEMMs. LDS layout (verified r3-r6):
// A rows: la = qm*128 + wr*64 + i*16 + (lane&15) holds tile row wr*128+qm*64+i*16+(lane&15)
// byte(l,slot s) = l*128 + (s^(l&7))*16; staged linear-dest with inverse-swz source.
#define GEMM_SETUP_AND_PIPELINE(Ag, Bg)                                                    \
  int t = threadIdx.x, lane = t & 63, wave = t >> 6;                                       \
  int wr = wave >> 2, wc = wave & 3;                                                       \
  int sl0 = ((lane >> 4) ^ (lane & 7)) * 16;                                               \
  int sl1 = (((lane >> 4) + 4) ^ (lane & 7)) * 16;                                         \
  int aLane = (wr * 64 + (lane & 15)) * 128;                                               \
  int bLane = (wc * 32 + (lane & 15)) * 128;                                               \
  const char* rA0k0 = (const char*)As0 + aLane + sl0;                                      \
  const char* rA0k1 = (const char*)As0 + aLane + sl1;                                      \
  const char* rA1k0 = (const char*)As1 + aLane + sl0;                                      \
  const char* rA1k1 = (const char*)As1 + aLane + sl1;                                      \
  const char* rB0k0 = (const char*)Bs0 + bLane + sl0;                                      \
  const char* rB0k1 = (const char*)Bs0 + bLane + sl1;                                      \
  const char* rB1k0 = (const char*)Bs1 + bLane + sl0;                                      \
  const char* rB1k1 = (const char*)Bs1 + bLane + sl1;                                      \
  char* dA0 = (char*)As0 + t * 16;                                                         \
  char* dA1 = (char*)As1 + t * 16;                                                         \
  char* dB0 = (char*)Bs0 + t * 16;                                                         \
  char* dB1 = (char*)Bs1 + t * 16;                                                         \
  int l3 = t >> 3;                                                                         \
  int sgE = ((t & 7) ^ (l3 & 7)) * 8;                                                      \
  const unsigned short* pA0 = Ag + (size_t)(m0 + l3) * 1024 + sgE;                         \
  const unsigned short* pA1 = pA0 + (size_t)128 * 1024;                                    \
  int nB0 = ((l3 >> 5) << 6) + (l3 & 31);                                                  \
  const unsigned short* pB0 = Bg + (size_t)(n0 + nB0) * 1024 + sgE;                        \
  const unsigned short* pB1 = pB0 + (size_t)128 * 1024;                                    \
  f32x4 acc[8][4] = {};                                                                    \
  /* prologue: 7 half-tile slots: A0h0,B0h0,B0h1,A0h1,A1h0,B1h0,B1h1 */                    \
  gload16(pA0, dA0); gload16(pA1, dA0 + 8192);                                             \
  gload16(pB0, dB0); gload16(pB1, dB0 + 8192);                                             \
  gload16(pB0 + 32768, dB0 + 16384); gload16(pB1 + 32768, dB0 + 16384 + 8192);             \
  gload16(pA0 + 65536, dA0 + 16384); gload16(pA1 + 65536, dA0 + 16384 + 8192);             \
  gload16(pA0 + 64, dA1); gload16(pA1 + 64, dA1 + 8192);                                   \
  gload16(pB0 + 64, dB1); gload16(pB1 + 64, dB1 + 8192);                                   \
  gload16(pB0 + 32768 + 64, dB1 + 16384); gload16(pB1 + 32768 + 64, dB1 + 16384 + 8192);   \
  vwait<6>();                                                                              \
  bar();                                                                                   \
  _Pragma("unroll 1") for (int kt = 0; kt < 14; kt += 2) {                                 \
    ktile<true, true, 6>(rA0k0, rA0k1, rB0k0, rB0k1, dA1, dA0, dB0, pA0, pA1, pB0, pB1,    \
                         (kt + 1) * 64, (kt + 2) * 64, acc);                               \
    ktile<true, true, 6>(rA1k0, rA1k1, rB1k0, rB1k1, dA0, dA1, dB1, pA0, pA1, pB0, pB1,    \
                         (kt + 2) * 64, (kt + 3) * 64, acc);                               \
  }                                                                                        \
  ktile<true, false, 0>(rA0k0, rA0k1, rB0k0, rB0k1, dA1, dA0, dB0, pA0, pA1, pB0, pB1,     \
                        15 * 64, 0, acc);                                                  \
  ktile<false, false, -1>(rA1k0, rA1k1, rB1k0, rB1k1, dA0, dA1, dB1, pA0, pA1, pB0, pB1,   \
                          0, 0, acc);

__device__ __forceinline__ void tile_coords(int bid, int& m0, int& n0, int& nt) {
  // 1024 blocks, 8 XCDs, bijective; nt fastest within an XCD for A-panel L2 reuse
  int lin = (bid & 7) * 128 + (bid >> 3);
  int mt = lin >> 2;
  nt = lin & 3;
  m0 = mt * BM;
  n0 = nt * BN;
}

// ---------- prep: convert (2048 blocks) + transpose (512) + query partials (32) ----------
__global__ __launch_bounds__(256) void prep_kernel(
    const float* __restrict__ seq, unsigned short* __restrict__ seqb,
    const float* __restrict__ Wk, const float* __restrict__ Wg,
    unsigned short* __restrict__ WkT, unsigned short* __restrict__ WgT,
    const float* __restrict__ q, const float* __restrict__ Wq,
    float* __restrict__ qp) {
  __shared__ float smem[4160];
  int bid = blockIdx.x, t = threadIdx.x;
  if (bid < 2048) {
    size_t i = ((size_t)bid * 256 + t) * 8;
    const size_t stride = (size_t)2048 * 256 * 8;
    for (; i < (size_t)67108864; i += stride) {
      f32x4 v0 = *(const f32x4*)(seq + i);
      f32x4 v1 = *(const f32x4*)(seq + i + 4);
      ushort8 o;
#pragma unroll
      for (int k = 0; k < 4; ++k) { o[k] = f2bf(v0[k]); o[k + 4] = f2bf(v1[k]); }
      *(ushort8*)(seqb + i) = o;
    }
  } else if (bid < 2560) {
    int b2 = bid - 2048;
    int mat = b2 >> 8;
    int tid = b2 & 255;
    int tr = tid >> 4, tc = tid & 15;
    const float* src = mat ? Wg : Wk;
    unsigned short* dst = mat ? WgT : WkT;
    int r0 = tr * 64, c0 = tc * 64;
    int lr = t >> 6, lc = t & 63;
#pragma unroll
    for (int i = 0; i < 16; ++i) {
      int r = i * 4 + lr;
      smem[r * 65 + lc] = src[(size_t)(r0 + r) * 1024 + c0 + lc];
    }
    __syncthreads();
#pragma unroll
    for (int i = 0; i < 16; ++i) {
      int r = i * 4 + lr;
      dst[(size_t)(c0 + r) * 1024 + r0 + lc] = f2bf(smem[lc * 65 + r]);
    }
  } else {
    // query partials: qp[hc][b][a] = sum_{h in chunk} q[b][h]*Wq[h][a]
    int b3 = bid - 2560;           // 32 blocks
    int ac = b3 & 3, hc = b3 >> 2; // 4 a-chunks x 8 h-chunks
    int h0 = hc * 128;
    for (int i = t; i < 4096; i += 256) {
      int b = i >> 7, hh = i & 127;
      smem[b * 128 + hh] = q[(size_t)b * 1024 + h0 + hh];
    }
    __syncthreads();
    int a = ac * 256 + t;
    float acc[32] = {};
    for (int hh = 0; hh < 128; hh += 4) {
      float w0 = Wq[(size_t)(h0 + hh) * 1024 + a];
      float w1 = Wq[(size_t)(h0 + hh + 1) * 1024 + a];
      float w2 = Wq[(size_t)(h0 + hh + 2) * 1024 + a];
      float w3 = Wq[(size_t)(h0 + hh + 3) * 1024 + a];
#pragma unroll
      for (int b = 0; b < 32; ++b) {
        f32x4 qv = *(const f32x4*)&smem[b * 128 + hh];
        acc[b] += qv[0] * w0 + qv[1] * w1 + qv[2] * w2 + qv[3] * w3;
      }
    }
#pragma unroll
    for (int b = 0; b < 32; ++b) qp[((size_t)(hc * 32 + b)) * 1024 + a] = acc[b];
  }
}

// ---------- GEMM1: align = tanh(seqb@WkT^T + query) -> bf16 ----------
__global__ __launch_bounds__(512, 2) void gemm1_kernel(
    const unsigned short* __restrict__ seqb, const unsigned short* __restrict__ WkT,
    const float* __restrict__ qp, const float* __restrict__ bq,
    const float* __restrict__ bk, unsigned short* __restrict__ alignb) {
  __shared__ unsigned short As0[BM * BK], Bs0[BN * BK], As1[BM * BK], Bs1[BN * BK];
  int m0, n0, nt;
  tile_coords(blockIdx.x, m0, n0, nt);
  GEMM_SETUP_AND_PIPELINE(seqb, WkT)

  // epilogue: fold query reduce (8 partials + bq + bk), tanh, store bf16
  int bidx = m0 >> 11;  // 256-row tile stays in one batch (2048 % 256 == 0)
  float qv[4];
#pragma unroll
  for (int ni = 0; ni < 4; ++ni) {
    int col = n0 + wc * 64 + ni * 16 + (lane & 15);
    float s = bq[col] + bk[col];
#pragma unroll
    for (int hc = 0; hc < 8; ++hc) s += qp[((size_t)(hc * 32 + bidx)) * 1024 + col];
    qv[ni] = s;
  }
#pragma unroll
  for (int mi = 0; mi < 8; ++mi) {
    int row0 = m0 + wr * 128 + mi * 16 + ((lane >> 4) * 4);
#pragma unroll
    for (int ni = 0; ni < 4; ++ni) {
      int col = n0 + wc * 64 + ni * 16 + (lane & 15);
#pragma unroll
      for (int j = 0; j < 4; ++j) {
        float v = fast_tanh(acc[mi][ni][j] + qv[ni]);
        alignb[(size_t)(row0 + j) * 1024 + col] = f2bf(v);
      }
    }
  }
}

// ---------- GEMM2: scores_part[nt,row] = sum_col align*sigmoid(align@Wg+bg)*Ws ----------
__global__ __launch_bounds__(512, 2) void gemm2_kernel(
    const unsigned short* __restrict__ alignb, const unsigned short* __restrict__ WgT,
    const float* __restrict__ bg, const float* __restrict__ Ws,
    float* __restrict__ scores_part) {
  __shared__ unsigned short As0[BM * BK], Bs0[BN * BK], As1[BM * BK], Bs1[BN * BK];
  __shared__ float sred[BM * 4];
  int m0, n0, nt;
  tile_coords(blockIdx.x, m0, n0, nt);
  GEMM_SETUP_AND_PIPELINE(alignb, WgT)

#pragma unroll
  for (int mi = 0; mi < 8; ++mi) {
#pragma unroll
    for (int j = 0; j < 4; ++j) {
      int rloc = wr * 128 + mi * 16 + ((lane >> 4) * 4) + j;
      int row = m0 + rloc;
      float p = 0.f;
#pragma unroll
      for (int ni = 0; ni < 4; ++ni) {
        int col = n0 + wc * 64 + ni * 16 + (lane & 15);
        float gate = fast_sigmoid(acc[mi][ni][j] + bg[col]);
        float al = bf2f(alignb[(size_t)row * 1024 + col]);
        p += al * gate * Ws[col];
      }
      p += __shfl_xor(p, 1);
      p += __shfl_xor(p, 2);
      p += __shfl_xor(p, 4);
      p += __shfl_xor(p, 8);
      if ((lane & 15) == 0) sred[rloc * 4 + wc] = p;
    }
  }
  __syncthreads();
  if (t < 256)
    scores_part[(size_t)nt * 65536 + m0 + t] =
        sred[t * 4] + sred[t * 4 + 1] + sred[t * 4 + 2] + sred[t * 4 + 3];
}

// ---------- softmax over S=2048 per batch; writes weights output ----------
__global__ __launch_bounds__(256) void softmax_kernel(const float* __restrict__ sp,
                                                      float* __restrict__ wout) {
  __shared__ float red[256];
  int b = blockIdx.x, t = threadIdx.x;
  float sc[8];
  float lmax = -1e30f;
#pragma unroll
  for (int i = 0; i < 8; ++i) {
    int s = i * 256 + t;
    float v = 0.f;
#pragma unroll
    for (int n = 0; n < 4; ++n) v += sp[(size_t)n * 65536 + b * 2048 + s];
    sc[i] = v;
    lmax = fmaxf(lmax, v);
  }
  red[t] = lmax;
  __syncthreads();
  for (int off = 128; off > 0; off >>= 1) {
    if (t < off) red[t] = fmaxf(red[t], red[t + off]);
    __syncthreads();
  }
  float mx = red[0];
  __syncthreads();
  float lsum = 0.f;
#pragma unroll
  for (int i = 0; i < 8; ++i) {
    sc[i] = expf(sc[i] - mx);
    lsum += sc[i];
  }
  red[t] = lsum;
  __syncthreads();
  for (int off = 128; off > 0; off >>= 1) {
    if (t < off) red[t] += red[t + off];
    __syncthreads();
  }
  float inv = 1.f / red[0];
#pragma unroll
  for (int i = 0; i < 8; ++i) wout[(size_t)b * 2048 + i * 256 + t] = sc[i] * inv;
}

// ---------- context partials (bf16 seq read, 4 h per thread, 8 s-chunks) ----------
__global__ __launch_bounds__(256) void context_kernel(const unsigned short* __restrict__ seqb,
                                                      const float* __restrict__ wts,
                                                      float* __restrict__ ctx_part) {
  __shared__ float wsh[256];
  int b = blockIdx.x, t = threadIdx.x, s0 = blockIdx.z * 256;
  int h0 = t * 4;
  wsh[t] = wts[(size_t)b * 2048 + s0 + t];
  __syncthreads();
  float a0 = 0.f, a1 = 0.f, a2 = 0.f, a3 = 0.f;
  const unsigned short* p = seqb + ((size_t)b * 2048 + s0) * 1024 + h0;
#pragma unroll 4
  for (int s = 0; s < 256; ++s) {
    ushortx4 v = *(const ushortx4*)(p + (size_t)s * 1024);
    float w = wsh[s];
    a0 += w * bf2f(v[0]);
    a1 += w * bf2f(v[1]);
    a2 += w * bf2f(v[2]);
    a3 += w * bf2f(v[3]);
  }
  float* dst = ctx_part + (size_t)(blockIdx.z * 32 + b) * 1024 + h0;
  dst[0] = a0; dst[1] = a1; dst[2] = a2; dst[3] = a3;
}

// ---------- pre partials: Wo read ONCE. grid (16 k-chunks of 128, 4 h-chunks) ----------
__global__ __launch_bounds__(256) void pre_kernel(const float* __restrict__ ctx_part,
                                                  const float* __restrict__ q,
                                                  const float* __restrict__ Wo,
                                                  float* __restrict__ pre_part) {
  __shared__ float fin[32 * 128];
  int kc = blockIdx.x, hc = blockIdx.y, t = threadIdx.x;
  int k0 = kc * 128, h0 = hc * 256;
  for (int i = t; i < 4096; i += 256) {
    int b = i >> 7, kk = i & 127, k = k0 + kk;
    float f;
    if (k < 1024) {
      f = 0.f;
#pragma unroll
      for (int s = 0; s < 8; ++s) f += ctx_part[((size_t)(s * 32 + b)) * 1024 + k];
    } else {
      f = q[(size_t)b * 1024 + (k - 1024)];
    }
    fin[b * 128 + kk] = f;
  }
  __syncthreads();
  int h = h0 + t;
  float acc[32] = {};
  for (int kk = 0; kk < 128; kk += 4) {
    float w0 = Wo[(size_t)(k0 + kk) * 1024 + h];
    float w1 = Wo[(size_t)(k0 + kk + 1) * 1024 + h];
    float w2 = Wo[(size_t)(k0 + kk + 2) * 1024 + h];
    float w3 = Wo[(size_t)(k0 + kk + 3) * 1024 + h];
#pragma unroll
    for (int b = 0; b < 32; ++b) {
      f32x4 fv = *(const f32x4*)&fin[b * 128 + kk];
      acc[b] += fv[0] * w0 + fv[1] * w1 + fv[2] * w2 + fv[3] * w3;
    }
  }
#pragma unroll
  for (int b = 0; b < 32; ++b) pre_part[((size_t)(kc * 32 + b)) * 1024 + h] = acc[b];
}

// ---------- final: residual + layernorm ----------
__global__ __launch_bounds__(256) void ln_kernel(const float* __restrict__ pre_part,
                                                 const float* __restrict__ q,
                                                 const float* __restrict__ bo,
                                                 const float* __restrict__ gamma,
                                                 const float* __restrict__ beta,
                                                 float* __restrict__ outF) {
  __shared__ float red[256];
  int b = blockIdx.x, t = threadIdx.x;
  float v[4];
  float lsum = 0.f;
#pragma unroll
  for (int i = 0; i < 4; ++i) {
    int h = i * 256 + t;
    float x = bo[h] + q[(size_t)b * 1024 + h];
#pragma unroll
    for (int kc = 0; kc < 16; ++kc) x += pre_part[((size_t)(kc * 32 + b)) * 1024 + h];
    v[i] = x;
    lsum += x;
  }
  red[t] = lsum;
  __syncthreads();
  for (int off = 128; off > 0; off >>= 1) {
    if (t < off) red[t] += red[t + off];
    __syncthreads();
  }
  float mu = red[0] * (1.f / 1024.f);
  __syncthreads();
  float lv = 0.f;
#pragma unroll
  for (int i = 0; i < 4; ++i) {
    float d = v[i] - mu;
    lv += d * d;
  }
  red[t] = lv;
  __syncthreads();
  for (int off = 128; off > 0; off >>= 1) {
    if (t < off) red[t] += red[t + off];
    __syncthreads();
  }
  float var = red[0] * (1.f / 1024.f);
  float rs = rsqrtf(var + 1e-5f);
#pragma unroll
  for (int i = 0; i < 4; ++i) {
    int h = i * 256 + t;
    outF[(size_t)b * 1024 + h] = (v[i] - mu) * rs * gamma[h] + beta[h];
  }
}

// ---------- host ----------
extern "C" void kernel_launch(void* const* d_in, const int* in_sizes, int n_in,
                              void* d_out, int out_size, void* d_ws, size_t ws_size,
                              hipStream_t stream) {
  const float* seq = (const float*)d_in[0];
  const float* q = (const float*)d_in[1];
  const float* Wk = (const float*)d_in[2];
  const float* bk = (const float*)d_in[3];
  const float* Wq = (const float*)d_in[4];
  const float* bq = (const float*)d_in[5];
  const float* Wg = (const float*)d_in[6];
  const float* bg = (const float*)d_in[7];
  const float* Ws = (const float*)d_in[8];
  // d_in[9] = bs: softmax is shift-invariant, cancels everywhere it appears
  const float* Wo = (const float*)d_in[10];
  const float* bo = (const float*)d_in[11];
  const float* gamma = (const float*)d_in[12];
  const float* beta = (const float*)d_in[13];

  float* outF = (float*)d_out;         // fused [32,1024]
  float* outW = outF + 32 * 1024;      // weights [32,2048]

  char* ws = (char*)d_ws;
  unsigned short* alignb = (unsigned short*)ws;  ws += (size_t)134217728;  // [65536,1024] bf16
  unsigned short* seqb = (unsigned short*)ws;    ws += (size_t)134217728;  // [65536,1024] bf16
  unsigned short* WkT = (unsigned short*)ws;     ws += 2097152;            // [1024,1024] bf16
  unsigned short* WgT = (unsigned short*)ws;     ws += 2097152;
  float* qp = (float*)ws;                        ws += 1048576;            // [8,32,1024]
  float* scores_part = (float*)ws;               ws += 1048576;            // [4,65536]
  float* ctx_part = (float*)ws;                  ws += 1048576;            // [8,32,1024]
  float* pre_part = (float*)ws;                  ws += 2097152;            // [16,32,1024]
  if (ws_size < (size_t)(ws - (char*)d_ws)) return;  // insufficient scratch

  prep_kernel<<<2592, 256, 0, stream>>>(seq, seqb, Wk, Wg, WkT, WgT, q, Wq, qp);
  gemm1_kernel<<<1024, 512, 0, stream>>>(seqb, WkT, qp, bq, bk, alignb);
  gemm2_kernel<<<1024, 512, 0, stream>>>(alignb, WgT, bg, Ws, scores_part);
  softmax_kernel<<<32, 256, 0, stream>>>(scores_part, outW);
  context_kernel<<<dim3(32, 1, 8), 256, 0, stream>>>(seqb, outW, ctx_part);
  pre_kernel<<<dim3(16, 4), 256, 0, stream>>>(ctx_part, q, Wo, pre_part);
  ln_kernel<<<32, 256, 0, stream>>>(pre_part, q, bo, gamma, beta, outF);
}